// Round 1
// baseline (198.652 us; speedup 1.0000x reference)
//
#include <hip/hip_runtime.h>
#include <hip/hip_cooperative_groups.h>
#include <math.h>

namespace cg = cooperative_groups;

// Shapes from reference: B=4, N=256, D=128, M=128, C=128
#define BB 4
#define NN 256
#define DD 128
#define MM 128
#define CC 128
#define ROWS (BB * NN)   // 1024

static __device__ __forceinline__ float fast_exp2(float x) {
#if __has_builtin(__builtin_amdgcn_exp2f)
    return __builtin_amdgcn_exp2f(x);
#else
    return __exp2f(x);
#endif
}

static __device__ __forceinline__ float fast_rcp(float x) {
#if __has_builtin(__builtin_amdgcn_rcpf)
    return __builtin_amdgcn_rcpf(x);
#else
    return 1.0f / x;
#endif
}

// silu(x) = x / (1 + exp(-x)); exp(-x) = 2^(-x*log2(e))
static __device__ __forceinline__ float silu_f(float x) {
    float e = fast_exp2(-1.44269504088896340736f * x);
    return x * fast_rcp(1.0f + e);
}

// ---------------------------------------------------------------------------
// Fused cooperative kernel — ZERO workspace. The output buffer (512 KB ==
// ROWS*MM*4 exactly) doubles as pj scratch between grid syncs.
//   Phase 0: pi(+b1) -> LDS (only this block's 2 rows needed!), pj -> out.
//   grid.sync()  (pj fully published, device-scope fence across XCD L2s)
//   Phase A: S[r][m] = inv * sum_{j!=i} adj * silu(pi+pj)   (pj from out)
//   grid.sync()  (ALL blocks done reading pj -> safe to overwrite out)
//   Phase B: magg = S@W2 + beta*b2 ; t1 = silu(magg@Wc1+bc1) ;
//            out = t1@Wc2 + bc2.
// 512 blocks x 256 threads, ~41 KB LDS -> 2 blocks/CU co-resident (coop OK).
// ---------------------------------------------------------------------------
__global__ __launch_bounds__(256) void k_fused(const float* __restrict__ h,
                                               const float* __restrict__ adj,
                                               const float* __restrict__ W1a,
                                               const float* __restrict__ W1b,
                                               const float* __restrict__ b1,
                                               const float* __restrict__ W2,
                                               const float* __restrict__ b2,
                                               const float* __restrict__ Wc1,
                                               const float* __restrict__ bc1,
                                               const float* __restrict__ Wc2,
                                               const float* __restrict__ bc2,
                                               float* __restrict__ out) {
    __shared__ float sStage[64 * MM];  // 32 KB: weight / pj chunk staging
    __shared__ float sAdj[2][NN];      // 2 KB
    __shared__ float sRed[2][256];     // 2 KB
    __shared__ float sS[2 * MM];       // 1 KB: S rows (also t1 later)
    __shared__ float sB[2 * MM];       // 1 KB: magg
    __shared__ float sPi[2 * MM];      // 1 KB: pi + b1 (this block's 2 rows)
    __shared__ float sH[2 * DD];       // 1 KB
    __shared__ float sWred[2][4];

    const int t = threadIdx.x;
    const int blk = blockIdx.x;        // 512 blocks
    const int b = blk >> 7;            // batch (128 blocks per batch)
    const int i0 = (blk & 127) * 2;
    const int row0 = b * NN + i0;

    const int m = t & 127;
    const int half = t >> 7;           // row-within-pair

    // ---- Phase 0: pi -> sPi, pj -> out (scratch). Weights in 4 chunks.
    sH[t] = h[(size_t)row0 * DD + t];
    const float bias = b1[m];

    float accA = 0.0f, accB = 0.0f;
    for (int c = 0; c < 4; ++c) {
        __syncthreads();               // protects prev chunk readers (and sH on c=0)
        const float4* ga = (const float4*)(W1a + (size_t)c * 32 * MM);
        const float4* gb = (const float4*)(W1b + (size_t)c * 32 * MM);
        float4* la = (float4*)sStage;               // first 16 KB: W1a chunk
        float4* lb = (float4*)(sStage + 32 * MM);   // second 16 KB: W1b chunk
        #pragma unroll
        for (int i = 0; i < 4; ++i) {
            la[t + 256 * i] = ga[t + 256 * i];
            lb[t + 256 * i] = gb[t + 256 * i];
        }
        __syncthreads();

        #pragma unroll 8
        for (int dd = 0; dd < 32; ++dd) {
            const int d = c * 32 + dd;
            const float hv = sH[half * DD + d];      // wave-uniform broadcast
            accA = fmaf(hv, sStage[dd * MM + m], accA);
            accB = fmaf(hv, sStage[32 * MM + dd * MM + m], accB);
        }
    }
    sPi[half * MM + m] = accA + bias;
    out[(size_t)(row0 + half) * MM + m] = accB;      // pj scratch in out buffer

    // ---- adj staging + row sums (independent of pj; overlap before grid sync)
    const float* arow = adj + (size_t)row0 * NN;
    const float a0v = arow[t];
    const float a1v = arow[t + 256];
    sAdj[0][t] = a0v;
    sAdj[1][t] = a1v;

    float v0 = a0v, v1 = a1v;
    #pragma unroll
    for (int off = 32; off > 0; off >>= 1) {
        v0 += __shfl_xor(v0, off, 64);
        v1 += __shfl_xor(v1, off, 64);
    }
    if ((t & 63) == 0) { sWred[0][t >> 6] = v0; sWred[1][t >> 6] = v1; }
    __syncthreads();                   // covers sWred, sAdj, sPi writes
    const float A0 = sWred[0][0] + sWred[0][1] + sWred[0][2] + sWred[0][3];
    const float A1 = sWred[1][0] + sWred[1][1] + sWred[1][2] + sWred[1][3];
    const float aii0 = sAdj[0][i0];
    const float aii1 = sAdj[1][i0 + 1];
    const float pim0 = sPi[m];         // this block's 2 pi rows (all threads)
    const float pim1 = sPi[MM + m];
    __syncthreads();                   // all reads done before zeroing diagonal
    if (t == 0) { sAdj[0][i0] = 0.0f; sAdj[1][i0 + 1] = 0.0f; }

    const float inv0 = 1.0f / fmaxf(A0, 1.0f);
    const float inv1 = 1.0f / fmaxf(A1, 1.0f);
    const float bet0 = (A0 - aii0) * inv0;
    const float bet1 = (A1 - aii1) * inv1;

    // ---- grid sync #1: every block's pj rows are published (device scope)
    cg::this_grid().sync();

    // ---- Phase A: weighted-silu reduction over j (pj staged in 4 chunks)
    const float* __restrict__ pjB = out + (size_t)b * NN * MM;
    float acc0 = 0.0f, acc1 = 0.0f;
    for (int c = 0; c < 4; ++c) {
        __syncthreads();               // covers diagonal zeroing on c=0
        const float4* g = (const float4*)(pjB + (size_t)c * 64 * MM);
        float4* l = (float4*)sStage;
        #pragma unroll
        for (int i = 0; i < 8; ++i) l[t + 256 * i] = g[t + 256 * i];
        __syncthreads();

        #pragma unroll 8
        for (int jj = half; jj < 64; jj += 2) {
            const int j = c * 64 + jj;
            const float pjv = sStage[jj * MM + m];    // stride-1: conflict-free
            const float w0 = sAdj[0][j];              // wave-uniform broadcast
            const float w1 = sAdj[1][j];
            acc0 = fmaf(w0, silu_f(pim0 + pjv), acc0);
            acc1 = fmaf(w1, silu_f(pim1 + pjv), acc1);
        }
    }

    sRed[0][t] = acc0;
    sRed[1][t] = acc1;
    __syncthreads();
    if (t < 128) {
        sS[t] = (sRed[0][t] + sRed[0][t + 128]) * inv0;
    } else {
        const int k = t - 128;
        sS[MM + k] = (sRed[1][k] + sRed[1][k + 128]) * inv1;
    }

    // ---- grid sync #2: ALL pj reads drained; out may now be overwritten.
    // (Also makes sS writes visible block-locally.)
    cg::this_grid().sync();

    // ---- Phase B: 3-stage head. k = m, row = half. Full dot per thread.
    const float b2k  = b2[m];
    const float bc1k = bc1[m];
    const float bc2k = bc2[m];
    const float betr = (half == 0) ? bet0 : bet1;

    // Stage 1: magg = S@W2 + beta*b2  (sS -> sB)
    float acc = betr * b2k;
    for (int c = 0; c < 2; ++c) {
        __syncthreads();
        const float4* g = (const float4*)(W2 + (size_t)c * 64 * MM);
        float4* l = (float4*)sStage;
        #pragma unroll
        for (int i = 0; i < 8; ++i) l[t + 256 * i] = g[t + 256 * i];
        __syncthreads();
        #pragma unroll 8
        for (int dd = 0; dd < 64; ++dd) {
            const int d = c * 64 + dd;
            acc = fmaf(sS[half * MM + d], sStage[dd * MM + m], acc);
        }
    }
    sB[half * MM + m] = acc;

    // Stage 2: t1 = silu(magg@Wc1 + bc1)  (sB -> sS)
    acc = bc1k;
    for (int c = 0; c < 2; ++c) {
        __syncthreads();               // covers sB writes on c=0
        const float4* g = (const float4*)(Wc1 + (size_t)c * 64 * MM);
        float4* l = (float4*)sStage;
        #pragma unroll
        for (int i = 0; i < 8; ++i) l[t + 256 * i] = g[t + 256 * i];
        __syncthreads();
        #pragma unroll 8
        for (int dd = 0; dd < 64; ++dd) {
            const int d = c * 64 + dd;
            acc = fmaf(sB[half * MM + d], sStage[dd * MM + m], acc);
        }
    }
    __syncthreads();                   // sS readers (stage 1 src) done
    sS[half * MM + m] = silu_f(acc);

    // Stage 3: out = t1@Wc2 + bc2
    acc = bc2k;
    for (int c = 0; c < 2; ++c) {
        __syncthreads();               // covers sS writes on c=0
        const float4* g = (const float4*)(Wc2 + (size_t)c * 64 * MM);
        float4* l = (float4*)sStage;
        #pragma unroll
        for (int i = 0; i < 8; ++i) l[t + 256 * i] = g[t + 256 * i];
        __syncthreads();
        #pragma unroll 8
        for (int dd = 0; dd < 64; ++dd) {
            const int d = c * 64 + dd;
            acc = fmaf(sS[half * MM + d], sStage[dd * MM + m], acc);
        }
    }
    out[(size_t)(row0 + half) * CC + m] = acc;
}

// ---------------------------------------------------------------------------
// Fallback path (previous verified 2-kernel version, uses workspace) — only
// taken if the cooperative launch is rejected (e.g. by graph capture).
// ---------------------------------------------------------------------------
__global__ __launch_bounds__(256) void k_proj(const float* __restrict__ h,
                                              const float* __restrict__ W1a,
                                              const float* __restrict__ W1b,
                                              const float* __restrict__ b1,
                                              float* __restrict__ pibias,
                                              float* __restrict__ pj) {
    __shared__ float sWa[32 * MM];
    __shared__ float sWb[32 * MM];
    __shared__ float sH[2 * DD];

    const int t = threadIdx.x;
    const int m = t & 127;
    const int r = t >> 7;
    const int row0 = blockIdx.x * 2;

    const float bias = b1[m];
    sH[t] = h[(size_t)row0 * DD + t];

    float accA = 0.0f, accB = 0.0f;
    for (int c = 0; c < 4; ++c) {
        __syncthreads();
        const float4* ga = (const float4*)(W1a + (size_t)c * 32 * MM);
        const float4* gb = (const float4*)(W1b + (size_t)c * 32 * MM);
        float4* la = (float4*)sWa;
        float4* lb = (float4*)sWb;
        #pragma unroll
        for (int i = 0; i < 4; ++i) {
            la[t + 256 * i] = ga[t + 256 * i];
            lb[t + 256 * i] = gb[t + 256 * i];
        }
        __syncthreads();

        #pragma unroll 8
        for (int dd = 0; dd < 32; ++dd) {
            const int d = c * 32 + dd;
            const float hv = sH[r * DD + d];
            accA = fmaf(hv, sWa[dd * MM + m], accA);
            accB = fmaf(hv, sWb[dd * MM + m], accB);
        }
    }

    const int row = row0 + r;
    pibias[(size_t)row * MM + m] = accA + bias;
    pj[(size_t)row * MM + m]     = accB;
}

__global__ __launch_bounds__(256) void k_msgout(const float* __restrict__ adj,
                                                const float* __restrict__ pibias,
                                                const float* __restrict__ pj,
                                                const float* __restrict__ W2,
                                                const float* __restrict__ b2,
                                                const float* __restrict__ Wc1,
                                                const float* __restrict__ bc1,
                                                const float* __restrict__ Wc2,
                                                const float* __restrict__ bc2,
                                                float* __restrict__ out) {
    __shared__ float sStage[64 * MM];
    __shared__ float sAdj[2][NN];
    __shared__ float sRed[2][256];
    __shared__ float sS[2 * MM];
    __shared__ float sB[2 * MM];
    __shared__ float sWred[2][4];

    const int t = threadIdx.x;
    const int blk = blockIdx.x;
    const int b = blk >> 7;
    const int i0 = (blk & 127) * 2;
    const int row0 = b * NN + i0;

    const int m = t & 127;
    const int half = t >> 7;

    const float b2k  = b2[m];
    const float bc1k = bc1[m];
    const float bc2k = bc2[m];
    const float pim0 = pibias[(size_t)row0 * MM + m];
    const float pim1 = pibias[(size_t)(row0 + 1) * MM + m];

    const float* arow = adj + (size_t)row0 * NN;
    const float a0v = arow[t];
    const float a1v = arow[t + 256];
    sAdj[0][t] = a0v;
    sAdj[1][t] = a1v;
    __syncthreads();

    float v0 = a0v, v1 = a1v;
    #pragma unroll
    for (int off = 32; off > 0; off >>= 1) {
        v0 += __shfl_xor(v0, off, 64);
        v1 += __shfl_xor(v1, off, 64);
    }
    if ((t & 63) == 0) { sWred[0][t >> 6] = v0; sWred[1][t >> 6] = v1; }
    __syncthreads();
    const float A0 = sWred[0][0] + sWred[0][1] + sWred[0][2] + sWred[0][3];
    const float A1 = sWred[1][0] + sWred[1][1] + sWred[1][2] + sWred[1][3];
    const float aii0 = sAdj[0][i0];
    const float aii1 = sAdj[1][i0 + 1];
    __syncthreads();
    if (t == 0) { sAdj[0][i0] = 0.0f; sAdj[1][i0 + 1] = 0.0f; }

    const float inv0 = 1.0f / fmaxf(A0, 1.0f);
    const float inv1 = 1.0f / fmaxf(A1, 1.0f);
    const float bet0 = (A0 - aii0) * inv0;
    const float bet1 = (A1 - aii1) * inv1;

    const float* __restrict__ pjB = pj + (size_t)b * NN * MM;
    float acc0 = 0.0f, acc1 = 0.0f;
    for (int c = 0; c < 4; ++c) {
        __syncthreads();
        const float4* g = (const float4*)(pjB + (size_t)c * 64 * MM);
        float4* l = (float4*)sStage;
        #pragma unroll
        for (int i = 0; i < 8; ++i) l[t + 256 * i] = g[t + 256 * i];
        __syncthreads();

        #pragma unroll 8
        for (int jj = half; jj < 64; jj += 2) {
            const int j = c * 64 + jj;
            const float pjv = sStage[jj * MM + m];
            const float w0 = sAdj[0][j];
            const float w1 = sAdj[1][j];
            acc0 = fmaf(w0, silu_f(pim0 + pjv), acc0);
            acc1 = fmaf(w1, silu_f(pim1 + pjv), acc1);
        }
    }

    sRed[0][t] = acc0;
    sRed[1][t] = acc1;
    __syncthreads();
    if (t < 128) {
        sS[t] = (sRed[0][t] + sRed[0][t + 128]) * inv0;
    } else {
        const int k = t - 128;
        sS[MM + k] = (sRed[1][k] + sRed[1][k + 128]) * inv1;
    }

    const float betr = (half == 0) ? bet0 : bet1;

    float acc = betr * b2k;
    for (int c = 0; c < 2; ++c) {
        __syncthreads();
        const float4* g = (const float4*)(W2 + (size_t)c * 64 * MM);
        float4* l = (float4*)sStage;
        #pragma unroll
        for (int i = 0; i < 8; ++i) l[t + 256 * i] = g[t + 256 * i];
        __syncthreads();
        #pragma unroll 8
        for (int dd = 0; dd < 64; ++dd) {
            const int d = c * 64 + dd;
            acc = fmaf(sS[half * MM + d], sStage[dd * MM + m], acc);
        }
    }
    sB[half * MM + m] = acc;

    acc = bc1k;
    for (int c = 0; c < 2; ++c) {
        __syncthreads();
        const float4* g = (const float4*)(Wc1 + (size_t)c * 64 * MM);
        float4* l = (float4*)sStage;
        #pragma unroll
        for (int i = 0; i < 8; ++i) l[t + 256 * i] = g[t + 256 * i];
        __syncthreads();
        #pragma unroll 8
        for (int dd = 0; dd < 64; ++dd) {
            const int d = c * 64 + dd;
            acc = fmaf(sB[half * MM + d], sStage[dd * MM + m], acc);
        }
    }
    __syncthreads();
    sS[half * MM + m] = silu_f(acc);

    acc = bc2k;
    for (int c = 0; c < 2; ++c) {
        __syncthreads();
        const float4* g = (const float4*)(Wc2 + (size_t)c * 64 * MM);
        float4* l = (float4*)sStage;
        #pragma unroll
        for (int i = 0; i < 8; ++i) l[t + 256 * i] = g[t + 256 * i];
        __syncthreads();
        #pragma unroll 8
        for (int dd = 0; dd < 64; ++dd) {
            const int d = c * 64 + dd;
            acc = fmaf(sS[half * MM + d], sStage[dd * MM + m], acc);
        }
    }
    out[(size_t)(row0 + half) * CC + m] = acc;
}

extern "C" void kernel_launch(void* const* d_in, const int* in_sizes, int n_in,
                              void* d_out, int out_size, void* d_ws, size_t ws_size,
                              hipStream_t stream) {
    const float* h   = (const float*)d_in[0];
    const float* adj = (const float*)d_in[1];
    const float* W1a = (const float*)d_in[2];
    const float* W1b = (const float*)d_in[3];
    const float* b1  = (const float*)d_in[4];
    const float* W2  = (const float*)d_in[5];
    const float* b2  = (const float*)d_in[6];
    const float* Wc1 = (const float*)d_in[7];
    const float* bc1 = (const float*)d_in[8];
    const float* Wc2 = (const float*)d_in[9];
    const float* bc2 = (const float*)d_in[10];
    float* out = (float*)d_out;

    // Primary: fused cooperative kernel, ZERO workspace (out doubles as pj
    // scratch between grid syncs).
    void* args[] = {(void*)&h,   (void*)&adj, (void*)&W1a, (void*)&W1b,
                    (void*)&b1,  (void*)&W2,  (void*)&b2,  (void*)&Wc1,
                    (void*)&bc1, (void*)&Wc2, (void*)&bc2, (void*)&out};
    hipError_t err = hipLaunchCooperativeKernel((const void*)k_fused,
                                                dim3(ROWS / 2), dim3(256),
                                                args, 0, stream);

    if (err != hipSuccess) {
        // Fallback: previous verified 2-kernel path via workspace.
        float* ws = (float*)d_ws;
        float* pibias = ws;
        float* pj     = ws + (size_t)ROWS * MM;
        k_proj<<<ROWS / 2, 256, 0, stream>>>(h, W1a, W1b, b1, pibias, pj);
        k_msgout<<<ROWS / 2, 256, 0, stream>>>(adj, pibias, pj, W2, b2, Wc1,
                                               bc1, Wc2, bc2, out);
    }
}

// Round 2
// 99.290 us; speedup vs baseline: 2.0007x; 2.0007x over previous
//
#include <hip/hip_runtime.h>
#include <math.h>

// Shapes from reference: B=4, N=256, D=128, M=128, C=128
#define BB 4
#define NN 256
#define DD 128
#define MM 128
#define CC 128
#define ROWS (BB * NN)     // 1024
#define RPB 4              // rows per block
#define NBLK (ROWS / RPB)  // 256 blocks
#define TPB 512            // 8 waves

static __device__ __forceinline__ float fast_exp2(float x) {
#if __has_builtin(__builtin_amdgcn_exp2f)
    return __builtin_amdgcn_exp2f(x);
#else
    return __exp2f(x);
#endif
}

static __device__ __forceinline__ float fast_rcp(float x) {
#if __has_builtin(__builtin_amdgcn_rcpf)
    return __builtin_amdgcn_rcpf(x);
#else
    return 1.0f / x;
#endif
}

// silu(x) = x / (1 + exp(-x)); exp(-x) = 2^(-x*log2(e))
static __device__ __forceinline__ float silu_f(float x) {
    float e = fast_exp2(-1.44269504088896340736f * x);
    return x * fast_rcp(1.0f + e);
}

// ---------------------------------------------------------------------------
// Kernel A: pibias = h@W1a + b1 ; pj = h@W1b
// 256 blocks x 512 threads, 4 rows/block: m = t&127, q = t>>7 (one row per
// thread-quarter; full 128-d dot per thread). Weights staged in 2 chunks of
// (32+32) KB. Weight L2 traffic: 256 x 128 KB = 32 MB (half of the 2-row
// version). Compute is trivial; this kernel is staging-bound.
// ---------------------------------------------------------------------------
__global__ __launch_bounds__(TPB) void k_proj(const float* __restrict__ h,
                                              const float* __restrict__ W1a,
                                              const float* __restrict__ W1b,
                                              const float* __restrict__ b1,
                                              float* __restrict__ pibias,
                                              float* __restrict__ pj) {
    __shared__ float sWa[64 * MM];   // 32 KB chunk of W1a
    __shared__ float sWb[64 * MM];   // 32 KB chunk of W1b
    __shared__ float sH[RPB * DD];   // 2 KB

    const int t = threadIdx.x;
    const int m = t & 127;
    const int q = t >> 7;            // row within block
    const int row0 = blockIdx.x * RPB;

    const float bias = b1[m];        // early load

    // Stage 4 h rows (512 floats, one per thread).
    sH[t] = h[(size_t)row0 * DD + t];

    float accA = 0.0f, accB = 0.0f;
    for (int c = 0; c < 2; ++c) {
        __syncthreads();             // protects prev chunk readers (and sH on c=0)
        const float4* ga = (const float4*)(W1a + (size_t)c * 64 * MM);
        const float4* gb = (const float4*)(W1b + (size_t)c * 64 * MM);
        float4* la = (float4*)sWa;
        float4* lb = (float4*)sWb;
        #pragma unroll
        for (int i = 0; i < 4; ++i) {
            la[t + TPB * i] = ga[t + TPB * i];
            lb[t + TPB * i] = gb[t + TPB * i];
        }
        __syncthreads();

        #pragma unroll 8
        for (int dd = 0; dd < 64; ++dd) {
            const float hv = sH[q * DD + c * 64 + dd];  // wave-uniform broadcast
            accA = fmaf(hv, sWa[dd * MM + m], accA);
            accB = fmaf(hv, sWb[dd * MM + m], accB);
        }
    }

    // (row0+q)*MM + m == row0*MM + t  -> fully coalesced 2 KB store
    pibias[(size_t)row0 * MM + t] = accA + bias;
    pj[(size_t)row0 * MM + t]     = accB;
}

// ---------------------------------------------------------------------------
// Kernel B: fused msg + output head, 4 rows/block, 256 blocks x 512 threads.
// Thread (q = t>>7, m = t&127) owns row row0+q, column m.
// Phase A: S[q][m] = inv * sum_{j!=i} adj * silu(pi+pj); each thread iterates
//   ALL 256 j for its row -> no cross-thread reduction tree at all.
// Phase B: magg = S@W2 + beta*b2 ; t1 = silu(magg@Wc1+bc1) ; out = t1@Wc2+bc2.
//   Full 128-d dot per thread per stage.
// L2 traffic: pj 256x128KB = 32 MB, weights 256x192KB = 48 MB (both halved).
// ---------------------------------------------------------------------------
__global__ __launch_bounds__(TPB) void k_msgout(const float* __restrict__ adj,
                                                const float* __restrict__ pibias,
                                                const float* __restrict__ pj,
                                                const float* __restrict__ W2,
                                                const float* __restrict__ b2,
                                                const float* __restrict__ Wc1,
                                                const float* __restrict__ bc1,
                                                const float* __restrict__ Wc2,
                                                const float* __restrict__ bc2,
                                                float* __restrict__ out) {
    __shared__ float sStage[64 * MM];  // 32 KB: pj / weight chunk staging
    __shared__ float sAdj[RPB][NN];    // 4 KB
    __shared__ float sS[RPB * MM];     // 2 KB: S rows (also t1 later)
    __shared__ float sB[RPB * MM];     // 2 KB: magg
    __shared__ float sWred0[8];        // per-wave partial row sums (rows 0,1)
    __shared__ float sWred1[8];        // per-wave partial row sums (rows 2,3)

    const int t = threadIdx.x;
    const int blk = blockIdx.x;        // 256 blocks
    const int b = blk >> 6;            // batch (64 blocks per batch)
    const int i0 = (blk & 63) * RPB;   // first row (batch-local)
    const int row0 = b * NN + i0;

    const int m = t & 127;
    const int q = t >> 7;              // row within block
    const int w = t >> 6;              // wave id 0..7

    // Early independent loads.
    const float b2k  = b2[m];
    const float bc1k = bc1[m];
    const float bc2k = bc2[m];
    const float pim  = pibias[(size_t)(row0 + q) * MM + m];

    // Stage all 4 adj rows (1024 floats, 2 per thread).
    const float* arow = adj + (size_t)row0 * NN;
    const float a0v = arow[t];          // rows 0 (waves 0-3) / 1 (waves 4-7)
    const float a1v = arow[t + TPB];    // rows 2 (waves 0-3) / 3 (waves 4-7)
    float* sA = &sAdj[0][0];
    sA[t] = a0v;
    sA[t + TPB] = a1v;

    // Per-wave partial row sums (each wave's 64 lanes lie within one row).
    float v0 = a0v, v1 = a1v;
    #pragma unroll
    for (int off = 32; off > 0; off >>= 1) {
        v0 += __shfl_xor(v0, off, 64);
        v1 += __shfl_xor(v1, off, 64);
    }
    if ((t & 63) == 0) { sWred0[w] = v0; sWred1[w] = v1; }
    __syncthreads();                   // covers sA, sWred writes

    // Row sum for this thread's row q (4 wave-partials).
    float A;
    if (q < 2) {
        const int base = (q & 1) * 4;
        A = sWred0[base] + sWred0[base + 1] + sWred0[base + 2] + sWred0[base + 3];
    } else {
        const int base = (q & 1) * 4;
        A = sWred1[base] + sWred1[base + 1] + sWred1[base + 2] + sWred1[base + 3];
    }
    const float aii = sAdj[q][i0 + q];  // diagonal (broadcast per q)
    __syncthreads();                    // all aii reads done before zeroing
    if (t < RPB) sAdj[t][i0 + t] = 0.0f;

    const float inv  = 1.0f / fmaxf(A, 1.0f);
    const float bet  = (A - aii) * inv;
    const float npim = -1.44269504088896340736f * pim;

    // ---- Phase A: weighted-silu reduction over all 256 j (4 chunks of 64).
    const float* __restrict__ pjB = pj + (size_t)b * NN * MM;
    float acc = 0.0f;
    for (int c = 0; c < 4; ++c) {
        __syncthreads();               // covers diagonal zeroing on c=0
        const float4* g = (const float4*)(pjB + (size_t)c * 64 * MM);
        float4* l = (float4*)sStage;
        #pragma unroll
        for (int i = 0; i < 4; ++i) l[t + TPB * i] = g[t + TPB * i];
        __syncthreads();

        #pragma unroll 8
        for (int jj = 0; jj < 64; ++jj) {
            const float pjv = sStage[jj * MM + m];     // stride-1: conflict-free
            const float wgt = sAdj[q][c * 64 + jj];    // wave-uniform broadcast
            const float x   = pim + pjv;
            const float e   = fast_exp2(fmaf(-1.44269504088896340736f, pjv, npim));
            acc = fmaf(wgt, x * fast_rcp(1.0f + e), acc);
        }
    }
    sS[q * MM + m] = acc * inv;        // S row, no reduction tree needed

    // ---- Phase B: 3-stage head. Full 128-d dot per thread.

    // Stage 1: magg = S@W2 + beta*b2  (sS -> sB)
    float acc2 = bet * b2k;
    for (int c = 0; c < 2; ++c) {
        __syncthreads();               // c=0: covers sS writes + last pj readers
        const float4* g = (const float4*)(W2 + (size_t)c * 64 * MM);
        float4* l = (float4*)sStage;
        #pragma unroll
        for (int i = 0; i < 4; ++i) l[t + TPB * i] = g[t + TPB * i];
        __syncthreads();
        #pragma unroll 8
        for (int dd = 0; dd < 64; ++dd) {
            acc2 = fmaf(sS[q * MM + c * 64 + dd], sStage[dd * MM + m], acc2);
        }
    }
    sB[q * MM + m] = acc2;

    // Stage 2: t1 = silu(magg@Wc1 + bc1)  (sB -> sS)
    acc2 = bc1k;
    for (int c = 0; c < 2; ++c) {
        __syncthreads();               // c=0: covers sB writes
        const float4* g = (const float4*)(Wc1 + (size_t)c * 64 * MM);
        float4* l = (float4*)sStage;
        #pragma unroll
        for (int i = 0; i < 4; ++i) l[t + TPB * i] = g[t + TPB * i];
        __syncthreads();
        #pragma unroll 8
        for (int dd = 0; dd < 64; ++dd) {
            acc2 = fmaf(sB[q * MM + c * 64 + dd], sStage[dd * MM + m], acc2);
        }
    }
    sS[q * MM + m] = silu_f(acc2);     // stage-1 sS readers all past stage-2 syncs

    // Stage 3: out = t1@Wc2 + bc2
    acc2 = bc2k;
    for (int c = 0; c < 2; ++c) {
        __syncthreads();               // c=0: covers sS writes
        const float4* g = (const float4*)(Wc2 + (size_t)c * 64 * MM);
        float4* l = (float4*)sStage;
        #pragma unroll
        for (int i = 0; i < 4; ++i) l[t + TPB * i] = g[t + TPB * i];
        __syncthreads();
        #pragma unroll 8
        for (int dd = 0; dd < 64; ++dd) {
            acc2 = fmaf(sS[q * MM + c * 64 + dd], sStage[dd * MM + m], acc2);
        }
    }
    // (row0+q)*CC + m == row0*CC + t  -> fully coalesced 2 KB store
    out[(size_t)row0 * CC + t] = acc2;
}

extern "C" void kernel_launch(void* const* d_in, const int* in_sizes, int n_in,
                              void* d_out, int out_size, void* d_ws, size_t ws_size,
                              hipStream_t stream) {
    const float* h   = (const float*)d_in[0];
    const float* adj = (const float*)d_in[1];
    const float* W1a = (const float*)d_in[2];
    const float* W1b = (const float*)d_in[3];
    const float* b1  = (const float*)d_in[4];
    const float* W2  = (const float*)d_in[5];
    const float* b2  = (const float*)d_in[6];
    const float* Wc1 = (const float*)d_in[7];
    const float* bc1 = (const float*)d_in[8];
    const float* Wc2 = (const float*)d_in[9];
    const float* bc2 = (const float*)d_in[10];
    float* out = (float*)d_out;

    // Workspace (floats): pibias[1024*128] | pj[1024*128]
    float* ws = (float*)d_ws;
    float* pibias = ws;
    float* pj     = ws + (size_t)ROWS * MM;

    k_proj<<<NBLK, TPB, 0, stream>>>(h, W1a, W1b, b1, pibias, pj);
    k_msgout<<<NBLK, TPB, 0, stream>>>(adj, pibias, pj, W2, b2, Wc1, bc1,
                                       Wc2, bc2, out);
}

// Round 3
// 97.810 us; speedup vs baseline: 2.0310x; 1.0151x over previous
//
#include <hip/hip_runtime.h>
#include <math.h>

// Shapes from reference: B=4, N=256, D=128, M=128, C=128
#define BB 4
#define NN 256
#define DD 128
#define MM 128
#define CC 128
#define ROWS (BB * NN)     // 1024
#define RPB 4              // rows per block
#define NBLK (ROWS / RPB)  // 256 blocks (== CU count, 1 block/CU)
#define TPB 512            // 8 waves

#define L2E 1.44269504088896340736f

static __device__ __forceinline__ float fast_exp2(float x) {
#if __has_builtin(__builtin_amdgcn_exp2f)
    return __builtin_amdgcn_exp2f(x);
#else
    return __exp2f(x);
#endif
}

static __device__ __forceinline__ float fast_rcp(float x) {
#if __has_builtin(__builtin_amdgcn_rcpf)
    return __builtin_amdgcn_rcpf(x);
#else
    return 1.0f / x;
#endif
}

// silu(x) = x / (1 + exp(-x)); exp(-x) = 2^(-x*log2(e))
static __device__ __forceinline__ float silu_f(float x) {
    float e = fast_exp2(-L2E * x);
    return x * fast_rcp(1.0f + e);
}

#if __has_builtin(__builtin_amdgcn_global_load_lds)
#define HAS_GLDS 1
// async global->LDS, 16B per lane; LDS dest = wave-uniform base + lane*16
#define GLDS(gp, lp)                                                        \
    __builtin_amdgcn_global_load_lds(                                       \
        (const __attribute__((address_space(1))) void*)(gp),                \
        (__attribute__((address_space(3))) void*)(lp), 16, 0, 0)
#else
#define HAS_GLDS 0
#endif

// Linear burst stage: ITERS * 8 waves * 1KB chunks. Same layout either path.
template <int ITERS>
static __device__ __forceinline__ void stage_lin(float* lds, const float* g,
                                                 int t) {
#if HAS_GLDS
    const int wv = t >> 6, lane = t & 63;
    #pragma unroll
    for (int i = 0; i < ITERS; ++i) {
        const int c = i * 8 + wv;              // 256-float chunk id
        GLDS(g + (size_t)c * 256 + lane * 4, lds + c * 256);
    }
#else
    #pragma unroll
    for (int i = 0; i < ITERS; ++i)
        ((float4*)lds)[i * TPB + t] = ((const float4*)g)[i * TPB + t];
#endif
}

// ---------------------------------------------------------------------------
// Kernel A: pibias = h@W1a + b1 ; pj = h@W1b
// 256 blocks x 512 threads, 4 rows/block. ALL 128 KB of weights staged in ONE
// async burst, interleaved per d-row as [W1a[d][0..127] | W1b[d][0..127]] so
// the inner loop reads both with one ds_read2_b32 pair (offset1=128 dwords).
// 2 barriers total.
// ---------------------------------------------------------------------------
__global__ __launch_bounds__(TPB) void k_proj(const float* __restrict__ h,
                                              const float* __restrict__ W1a,
                                              const float* __restrict__ W1b,
                                              const float* __restrict__ b1,
                                              float* __restrict__ pibias,
                                              float* __restrict__ pj) {
    __shared__ float sW[128 * 256];  // 128 KB interleaved weight rows
    __shared__ float sH[RPB * DD];   // 2 KB

    const int t = threadIdx.x;
    const int m = t & 127;
    const int q = t >> 7;            // row within block
    const int row0 = blockIdx.x * RPB;

    sH[t] = h[(size_t)row0 * DD + t];

#if HAS_GLDS
    {
        const int wv = t >> 6, lane = t & 63;
        #pragma unroll
        for (int i = 0; i < 16; ++i) {
            const int r = i * 8 + wv;          // weight row d = r
            const float* g = (lane < 32)
                                 ? (W1a + (size_t)r * 128 + lane * 4)
                                 : (W1b + (size_t)r * 128 + (lane - 32) * 4);
            GLDS(g, &sW[r * 256]);
        }
    }
#else
    #pragma unroll
    for (int i = 0; i < 16; ++i) {
        const int f = i * TPB + t;             // float4 index in sW
        const int r = f >> 6;                  // weight row
        const int c4 = f & 63;                 // float4 within 256-float row
        const float4 v = (c4 < 32)
                             ? ((const float4*)(W1a + (size_t)r * 128))[c4]
                             : ((const float4*)(W1b + (size_t)r * 128))[c4 - 32];
        ((float4*)sW)[f] = v;
    }
#endif

    const float bias = b1[m];
    __syncthreads();                 // drains gloads (vmcnt0) + sH

    float accA = 0.0f, accB = 0.0f;
    const float* sHq = &sH[q * DD];
    #pragma unroll 8
    for (int d = 0; d < 128; d += 2) {
        const float2 hv = *(const float2*)&sHq[d];   // wave-uniform b64
        accA = fmaf(hv.x, sW[d * 256 + m], accA);          // read2 pair
        accB = fmaf(hv.x, sW[d * 256 + 128 + m], accB);
        accA = fmaf(hv.y, sW[(d + 1) * 256 + m], accA);    // read2 pair
        accB = fmaf(hv.y, sW[(d + 1) * 256 + 128 + m], accB);
    }

    // (row0+q)*MM + m == row0*MM + t  -> fully coalesced stores
    pibias[(size_t)row0 * MM + t] = accA + bias;
    pj[(size_t)row0 * MM + t]     = accB;
}

// ---------------------------------------------------------------------------
// Kernel B: fused msg + output head. 256 blocks x 512 threads, 4 rows/block.
// ENTIRE pj batch-slice (128 KB) staged once into LDS -> Phase A has no
// interior staging barriers. Diagonal handled by subtraction (no zeroing
// barriers). Phase B weights streamed into the recycled sPJ region, each
// staged UNDER the previous stage's compute. 5 barriers total.
// Phase A silu pairs 2 elements per v_rcp (1.5 trans/elem instead of 2).
// ---------------------------------------------------------------------------
__global__ __launch_bounds__(TPB) void k_msgout(const float* __restrict__ adj,
                                                const float* __restrict__ pibias,
                                                const float* __restrict__ pj,
                                                const float* __restrict__ W2,
                                                const float* __restrict__ b2,
                                                const float* __restrict__ Wc1,
                                                const float* __restrict__ bc1,
                                                const float* __restrict__ Wc2,
                                                const float* __restrict__ bc2,
                                                float* __restrict__ out) {
    __shared__ float sPJ[256 * MM];    // 128 KB: pj slice; later W2|Wc1, Wc2
    __shared__ float sAdj[RPB][NN];    // 4 KB
    __shared__ float sS[RPB * MM];     // 2 KB: S rows, later t1
    __shared__ float sB[RPB * MM];     // 2 KB: magg
    __shared__ float sWr0[8];          // per-wave adj partial sums rows 0/1
    __shared__ float sWr1[8];          // rows 2/3

    const int t = threadIdx.x;
    const int blk = blockIdx.x;        // 256 blocks
    const int b = blk >> 6;            // batch
    const int i0 = (blk & 63) * RPB;   // first row (batch-local)
    const int row0 = b * NN + i0;

    const int m = t & 127;
    const int q = t >> 7;              // row within block
    const int w = t >> 6;              // wave id 0..7

    // ---- issue the full pj batch-slice stage FIRST (async, 128 KB)
    const float* __restrict__ pjB = pj + (size_t)b * NN * MM;
    stage_lin<16>(sPJ, pjB, t);

    // ---- early loads + adj staging / row sums (overlaps staging in flight)
    const float pim  = pibias[(size_t)(row0 + q) * MM + m];
    const float b2k  = b2[m];
    const float bc1k = bc1[m];
    const float bc2k = bc2[m];

    const float* arow = adj + (size_t)row0 * NN;
    const float a0v = arow[t];          // rows 0/1
    const float a1v = arow[t + TPB];    // rows 2/3
    float* sA = &sAdj[0][0];
    sA[t] = a0v;
    sA[t + TPB] = a1v;

    float v0 = a0v, v1 = a1v;
    #pragma unroll
    for (int off = 32; off > 0; off >>= 1) {
        v0 += __shfl_xor(v0, off, 64);
        v1 += __shfl_xor(v1, off, 64);
    }
    if ((t & 63) == 0) { sWr0[w] = v0; sWr1[w] = v1; }

    __syncthreads();   // B1: sPJ staged (vmcnt0), sAdj + sWr visible

    float A;
    {
        const int base = (q & 1) * 4;
        A = (q < 2) ? (sWr0[base] + sWr0[base + 1] + sWr0[base + 2] + sWr0[base + 3])
                    : (sWr1[base] + sWr1[base + 1] + sWr1[base + 2] + sWr1[base + 3]);
    }
    const float aii = sAdj[q][i0 + q];   // diagonal weight (never zeroed)
    const float inv = 1.0f / fmaxf(A, 1.0f);
    const float bet = (A - aii) * inv;
    const float npim = -L2E * pim;

    // Diagonal correction term (row i0+q may live in the half of sPJ that
    // gets recycled for W2 below -- read it now, while everything is valid).
    float acc = -aii * silu_f(pim + sPJ[(i0 + q) * MM + m]);

    // ---- Phase A first half: j in [0,128)  (no barriers inside)
    #pragma unroll 8
    for (int j = 0; j < 128; j += 2) {
        const float p0 = sPJ[j * MM + m];            // read2 pair
        const float p1 = sPJ[(j + 1) * MM + m];
        const float2 wv = *(const float2*)&sAdj[q][j];  // uniform b64
        const float x0 = pim + p0, x1 = pim + p1;
        const float e0 = fast_exp2(fmaf(-L2E, p0, npim));
        const float e1 = fast_exp2(fmaf(-L2E, p1, npim));
        const float d0 = 1.0f + e0, d1 = 1.0f + e1;
        const float rp = fast_rcp(d0 * d1);          // one rcp for two silus
        acc = fmaf(wv.x * x0, rp * d1, acc);
        acc = fmaf(wv.y * x1, rp * d0, acc);
    }

    __syncthreads();   // B2: all threads past first half of sPJ
    // W2 (64 KB) streams into the consumed first half, under 2nd-half compute
    stage_lin<8>(sPJ, W2, t);

    // ---- Phase A second half: j in [128,256)
    #pragma unroll 8
    for (int j = 128; j < 256; j += 2) {
        const float p0 = sPJ[j * MM + m];
        const float p1 = sPJ[(j + 1) * MM + m];
        const float2 wv = *(const float2*)&sAdj[q][j];
        const float x0 = pim + p0, x1 = pim + p1;
        const float e0 = fast_exp2(fmaf(-L2E, p0, npim));
        const float e1 = fast_exp2(fmaf(-L2E, p1, npim));
        const float d0 = 1.0f + e0, d1 = 1.0f + e1;
        const float rp = fast_rcp(d0 * d1);
        acc = fmaf(wv.x * x0, rp * d1, acc);
        acc = fmaf(wv.y * x1, rp * d0, acc);
    }
    sS[q * MM + m] = acc * inv;        // S row (each thread owns full j-sum)

    __syncthreads();   // B3: W2 staged, sS visible, 2nd-half sPJ reads done
    // Wc1 (64 KB) streams into the second half, under stage-1 compute
    stage_lin<8>(sPJ + 16384, Wc1, t);

    // ---- Stage 1: magg = S@W2 + beta*b2
    float acc2 = bet * b2k;
    {
        const float* sSr = &sS[q * MM];
        #pragma unroll 8
        for (int d = 0; d < 128; d += 2) {
            const float2 sv = *(const float2*)&sSr[d];   // uniform b64
            acc2 = fmaf(sv.x, sPJ[d * MM + m], acc2);    // read2 pair
            acc2 = fmaf(sv.y, sPJ[(d + 1) * MM + m], acc2);
        }
    }
    sB[q * MM + m] = acc2;

    __syncthreads();   // B4: Wc1 staged, sB visible, W2 reads done
    // Wc2 (64 KB) streams into the first half again, under stage-2 compute
    stage_lin<8>(sPJ, Wc2, t);

    // ---- Stage 2: t1 = silu(magg@Wc1 + bc1)
    acc2 = bc1k;
    {
        const float* sBr = &sB[q * MM];
        const float* sW1 = sPJ + 16384;
        #pragma unroll 8
        for (int d = 0; d < 128; d += 2) {
            const float2 sv = *(const float2*)&sBr[d];
            acc2 = fmaf(sv.x, sW1[d * MM + m], acc2);
            acc2 = fmaf(sv.y, sW1[(d + 1) * MM + m], acc2);
        }
    }
    sS[q * MM + m] = silu_f(acc2);     // t1 (stage-1 sS readers done pre-B4)

    __syncthreads();   // B5: Wc2 staged, t1 visible, Wc1 reads done

    // ---- Stage 3: out = t1@Wc2 + bc2
    acc2 = bc2k;
    {
        const float* sSr = &sS[q * MM];
        #pragma unroll 8
        for (int d = 0; d < 128; d += 2) {
            const float2 sv = *(const float2*)&sSr[d];
            acc2 = fmaf(sv.x, sPJ[d * MM + m], acc2);
            acc2 = fmaf(sv.y, sPJ[(d + 1) * MM + m], acc2);
        }
    }
    // (row0+q)*CC + m == row0*CC + t  -> fully coalesced store
    out[(size_t)row0 * CC + t] = acc2;
}

extern "C" void kernel_launch(void* const* d_in, const int* in_sizes, int n_in,
                              void* d_out, int out_size, void* d_ws, size_t ws_size,
                              hipStream_t stream) {
    const float* h   = (const float*)d_in[0];
    const float* adj = (const float*)d_in[1];
    const float* W1a = (const float*)d_in[2];
    const float* W1b = (const float*)d_in[3];
    const float* b1  = (const float*)d_in[4];
    const float* W2  = (const float*)d_in[5];
    const float* b2  = (const float*)d_in[6];
    const float* Wc1 = (const float*)d_in[7];
    const float* bc1 = (const float*)d_in[8];
    const float* Wc2 = (const float*)d_in[9];
    const float* bc2 = (const float*)d_in[10];
    float* out = (float*)d_out;

    // Workspace (floats): pibias[1024*128] | pj[1024*128]
    float* ws = (float*)d_ws;
    float* pibias = ws;
    float* pj     = ws + (size_t)ROWS * MM;

    k_proj<<<NBLK, TPB, 0, stream>>>(h, W1a, W1b, b1, pibias, pj);
    k_msgout<<<NBLK, TPB, 0, stream>>>(adj, pibias, pj, W2, b2, Wc1, bc1,
                                       Wc2, bc2, out);
}

// Round 4
// 97.651 us; speedup vs baseline: 2.0343x; 1.0016x over previous
//
#include <hip/hip_runtime.h>
#include <math.h>

// Shapes from reference: B=4, N=256, D=128, M=128, C=128
#define BB 4
#define NN 256
#define DD 128
#define MM 128
#define CC 128
#define ROWS (BB * NN)     // 1024
#define RPB 4              // rows per block
#define NBLK (ROWS / RPB)  // 256 blocks (== CU count, 1 block/CU)
#define TPB 512            // 8 waves

#define L2E 1.44269504088896340736f

// Workspace float offsets
#define WS_PIB   0          // pibias [1024][128]
#define WS_PJLO  131072     // pjT lo-half [4][128 m][128 j<128] (pre-swizzled)
#define WS_PJHI  196608     // pjT hi-half [4][128 m][128 j>=128]
#define WS_W2T   262144     // W2^T  [128][128] (pre-swizzled)
#define WS_WC1T  278528     // Wc1^T
#define WS_WC2T  294912     // Wc2^T

static __device__ __forceinline__ float fast_exp2(float x) {
#if __has_builtin(__builtin_amdgcn_exp2f)
    return __builtin_amdgcn_exp2f(x);
#else
    return __exp2f(x);
#endif
}

static __device__ __forceinline__ float fast_rcp(float x) {
#if __has_builtin(__builtin_amdgcn_rcpf)
    return __builtin_amdgcn_rcpf(x);
#else
    return 1.0f / x;
#endif
}

// silu(x) = x / (1 + exp(-x))
static __device__ __forceinline__ float silu_f(float x) {
    float e = fast_exp2(-L2E * x);
    return x * fast_rcp(1.0f + e);
}

#if __has_builtin(__builtin_amdgcn_global_load_lds)
#define HAS_GLDS 1
#define GLDS(gp, lp)                                                        \
    __builtin_amdgcn_global_load_lds(                                       \
        (const __attribute__((address_space(1))) void*)(gp),                \
        (__attribute__((address_space(3))) void*)(lp), 16, 0, 0)
#else
#define HAS_GLDS 0
#endif

// Linear burst stage: ITERS * 8 waves * 1KB chunks (source already laid out /
// pre-swizzled in global; LDS image == byte copy of source).
template <int ITERS>
static __device__ __forceinline__ void stage_lin(float* lds, const float* g,
                                                 int t) {
#if HAS_GLDS
    const int wv = t >> 6, lane = t & 63;
    #pragma unroll
    for (int i = 0; i < ITERS; ++i) {
        const int c = i * 8 + wv;              // 256-float chunk id
        GLDS(g + (size_t)c * 256 + lane * 4, lds + c * 256);
    }
#else
    #pragma unroll
    for (int i = 0; i < ITERS; ++i)
        ((float4*)lds)[i * TPB + t] = ((const float4*)g)[i * TPB + t];
#endif
}

// ---------------------------------------------------------------------------
// Kernel A: pibias = h@W1a + b1 (linear layout) ; pjT = (h@W1b)^T per batch,
// written PRE-SWIZZLED (16B slot ^= (m&7)) so k_msgout stages it linearly and
// reads rows with swizzled ds_read_b128. Blocks 0-11 additionally transpose
// W2/Wc1/Wc2 into workspace (pre-swizzled) for Phase B row reads.
// ---------------------------------------------------------------------------
__global__ __launch_bounds__(TPB) void k_proj(const float* __restrict__ h,
                                              const float* __restrict__ W1a,
                                              const float* __restrict__ W1b,
                                              const float* __restrict__ b1,
                                              const float* __restrict__ W2,
                                              const float* __restrict__ Wc1,
                                              const float* __restrict__ Wc2,
                                              float* __restrict__ ws) {
    __shared__ __align__(16) float sW[128 * 256];  // 128 KB interleaved rows
    __shared__ float sH[RPB * DD];                 // 2 KB

    const int t = threadIdx.x;
    const int m = t & 127;
    const int q = t >> 7;            // row within block
    const int row0 = blockIdx.x * RPB;

    sH[t] = h[(size_t)row0 * DD + t];

#if HAS_GLDS
    {
        const int wv = t >> 6, lane = t & 63;
        #pragma unroll
        for (int i = 0; i < 16; ++i) {
            const int r = i * 8 + wv;          // weight row d = r
            const float* g = (lane < 32)
                                 ? (W1a + (size_t)r * 128 + lane * 4)
                                 : (W1b + (size_t)r * 128 + (lane - 32) * 4);
            GLDS(g, &sW[r * 256]);
        }
    }
#else
    #pragma unroll
    for (int i = 0; i < 16; ++i) {
        const int f = i * TPB + t;             // float4 index in sW
        const int r = f >> 6;                  // weight row
        const int c4 = f & 63;                 // float4 within 256-float row
        const float4 v = (c4 < 32)
                             ? ((const float4*)(W1a + (size_t)r * 128))[c4]
                             : ((const float4*)(W1b + (size_t)r * 128))[c4 - 32];
        ((float4*)sW)[f] = v;
    }
#endif

    const float bias = b1[m];
    __syncthreads();                 // drains gloads + sH

    float accA = 0.0f, accB = 0.0f;
    const float* sHq = &sH[q * DD];
    #pragma unroll 8
    for (int d = 0; d < 128; d += 2) {
        const float2 hv = *(const float2*)&sHq[d];   // wave-uniform b64
        accA = fmaf(hv.x, sW[d * 256 + m], accA);
        accB = fmaf(hv.x, sW[d * 256 + 128 + m], accB);
        accA = fmaf(hv.y, sW[(d + 1) * 256 + m], accA);
        accB = fmaf(hv.y, sW[(d + 1) * 256 + 128 + m], accB);
    }

    // pibias linear (coalesced)
    ws[WS_PIB + (size_t)row0 * MM + t] = accA + bias;

    // pjT pre-swizzled scatter write: pjT[m][jloc], 16B-slot ^= (m&7)
    {
        const int b    = row0 >> 8;
        const int jloc = (row0 & 255) + q;     // batch-local column
        const int half = jloc >> 7;
        const int jj   = jloc & 127;
        const int c16  = jj >> 2;
        const int off  = (half ? WS_PJHI : WS_PJLO) + b * 16384 + m * 128 +
                         (((c16 ^ (m & 7)) << 2) | (jj & 3));
        ws[off] = accB;
    }

    // Weight transposes (pre-swizzled): blocks 0-11, 32 d-rows each.
    if (blockIdx.x < 12) {
        const int blk = blockIdx.x;
        const float* Wsrc = (blk < 4) ? W2 : (blk < 8) ? Wc1 : Wc2;
        float* Wdst = ws + ((blk < 4) ? WS_W2T : (blk < 8) ? WS_WC1T : WS_WC2T);
        const int d0 = (blk & 3) * 32;
        const int k = m;
        #pragma unroll
        for (int i = 0; i < 8; ++i) {
            const int d = d0 + (q << 3) + i;
            const float v = Wsrc[(size_t)d * 128 + k];   // coalesced over k
            Wdst[k * 128 + ((((d >> 2) ^ (k & 7)) << 2) | (d & 3))] = v;
        }
    }
}

// ---------------------------------------------------------------------------
// Kernel B: fused msg + output head. 256 blocks x 512 threads, 4 rows/block.
// All heavy LDS operands are ROW reads via swizzled ds_read_b128:
//   Phase A: pjT rows (64 b128/thread), adj via wave-uniform float4 loads.
//   Phase B: transposed weights (32 b128/thread/stage) + uniform float4 S.
// 5 barriers; Phase-B weights staged under the previous phase's compute.
// ---------------------------------------------------------------------------
__global__ __launch_bounds__(TPB) void k_msgout(const float* __restrict__ adj,
                                                const float* __restrict__ b2,
                                                const float* __restrict__ bc1,
                                                const float* __restrict__ bc2,
                                                const float* __restrict__ ws,
                                                float* __restrict__ out) {
    __shared__ __align__(16) float sLo[16384];  // 64 KB: pjT lo / W2T / Wc2T
    __shared__ __align__(16) float sHi[16384];  // 64 KB: pjT hi / Wc1T
    __shared__ __align__(16) float sS[RPB * MM];  // S rows, later t1
    __shared__ __align__(16) float sB[RPB * MM];  // magg
    __shared__ float sWr0[8], sWr1[8];

    const int t = threadIdx.x;
    const int blk = blockIdx.x;        // 256 blocks
    const int b = blk >> 6;            // batch
    const int i0 = (blk & 63) * RPB;   // first row (batch-local)
    const int row0 = b * NN + i0;

    const int m = t & 127;
    const int q = t >> 7;              // row within block (uniform per wave)
    const int w = t >> 6;              // wave id
    const int swz = m & 7;

    // ---- issue pjT staging (128 KB total, pre-swizzled source -> linear)
    stage_lin<8>(sLo, ws + WS_PJLO + b * 16384, t);
    stage_lin<8>(sHi, ws + WS_PJHI + b * 16384, t);

    // ---- early loads (overlap with staging)
    const float pim  = ws[WS_PIB + (size_t)row0 * MM + t];  // pibias[row0+q][m]
    const float b2k  = b2[m];
    const float bc1k = bc1[m];
    const float bc2k = bc2[m];

    // adj row sums via coalesced vector loads + wave shuffle
    const float* arow = adj + (size_t)row0 * NN;
    const float a0v = arow[t];          // rows 0/1
    const float a1v = arow[t + TPB];    // rows 2/3
    float v0 = a0v, v1 = a1v;
    #pragma unroll
    for (int off = 32; off > 0; off >>= 1) {
        v0 += __shfl_xor(v0, off, 64);
        v1 += __shfl_xor(v1, off, 64);
    }
    if ((t & 63) == 0) { sWr0[w] = v0; sWr1[w] = v1; }

    // wave-uniform adj row pointer (scalarized)
    const int srow = __builtin_amdgcn_readfirstlane(row0 + q);
    const float* __restrict__ adjr = adj + (size_t)srow * NN;

    __syncthreads();   // B1: pjT staged, sWr visible

    float A;
    {
        const int base = (q & 1) * 4;
        A = (q < 2) ? (sWr0[base] + sWr0[base + 1] + sWr0[base + 2] + sWr0[base + 3])
                    : (sWr1[base] + sWr1[base + 1] + sWr1[base + 2] + sWr1[base + 3]);
    }
    const float aii = adjr[srow & 255];     // diagonal (uniform scalar load)
    const float inv = 1.0f / fmaxf(A, 1.0f);
    const float bet = (A - aii) * inv;
    const float npim = -L2E * pim;

    // Diagonal correction (subtract instead of zeroing adj)
    float acc;
    {
        const int iloc = i0 + q;
        const int jj = iloc & 127;
        const float* base = (iloc < 128) ? sLo : sHi;
        const float pjd = base[m * 128 + ((((jj >> 2) ^ swz) << 2) | (jj & 3))];
        acc = -aii * silu_f(pim + pjd);
    }

    // ---- Phase A, j in [0,128): swizzled b128 rows of pjT-lo
    const float* rowLo = sLo + m * 128;
    #pragma unroll 8
    for (int j4 = 0; j4 < 32; ++j4) {
        const float4 pv = *(const float4*)(rowLo + ((j4 ^ swz) << 2));
        const float4 av = *(const float4*)(adjr + (j4 << 2));   // uniform
        const float x0 = pim + pv.x, x1 = pim + pv.y;
        const float x2 = pim + pv.z, x3 = pim + pv.w;
        const float e0 = fast_exp2(fmaf(-L2E, pv.x, npim));
        const float e1 = fast_exp2(fmaf(-L2E, pv.y, npim));
        const float e2 = fast_exp2(fmaf(-L2E, pv.z, npim));
        const float e3 = fast_exp2(fmaf(-L2E, pv.w, npim));
        const float d0 = 1.0f + e0, d1 = 1.0f + e1;
        const float d2 = 1.0f + e2, d3 = 1.0f + e3;
        const float r01 = fast_rcp(d0 * d1), r23 = fast_rcp(d2 * d3);
        acc = fmaf(av.x * x0, r01 * d1, acc);
        acc = fmaf(av.y * x1, r01 * d0, acc);
        acc = fmaf(av.z * x2, r23 * d3, acc);
        acc = fmaf(av.w * x3, r23 * d2, acc);
    }

    __syncthreads();   // B2: all lo reads done
    stage_lin<8>(sLo, ws + WS_W2T, t);   // W2^T -> lo (under hi compute)

    // ---- Phase A, j in [128,256)
    const float* rowHi = sHi + m * 128;
    #pragma unroll 8
    for (int j4 = 0; j4 < 32; ++j4) {
        const float4 pv = *(const float4*)(rowHi + ((j4 ^ swz) << 2));
        const float4 av = *(const float4*)(adjr + 128 + (j4 << 2));
        const float x0 = pim + pv.x, x1 = pim + pv.y;
        const float x2 = pim + pv.z, x3 = pim + pv.w;
        const float e0 = fast_exp2(fmaf(-L2E, pv.x, npim));
        const float e1 = fast_exp2(fmaf(-L2E, pv.y, npim));
        const float e2 = fast_exp2(fmaf(-L2E, pv.z, npim));
        const float e3 = fast_exp2(fmaf(-L2E, pv.w, npim));
        const float d0 = 1.0f + e0, d1 = 1.0f + e1;
        const float d2 = 1.0f + e2, d3 = 1.0f + e3;
        const float r01 = fast_rcp(d0 * d1), r23 = fast_rcp(d2 * d3);
        acc = fmaf(av.x * x0, r01 * d1, acc);
        acc = fmaf(av.y * x1, r01 * d0, acc);
        acc = fmaf(av.z * x2, r23 * d3, acc);
        acc = fmaf(av.w * x3, r23 * d2, acc);
    }
    sS[(q << 7) + m] = acc * inv;

    __syncthreads();   // B3: W2T staged, sS visible, hi reads done
    stage_lin<8>(sHi, ws + WS_WC1T, t);  // Wc1^T -> hi (under stage-1)

    // ---- Stage 1: magg = S@W2 + beta*b2   (weights: swizzled b128 rows)
    float acc2 = bet * b2k;
    {
        const float* rw = sLo + m * 128;
        #pragma unroll 8
        for (int d4 = 0; d4 < 32; ++d4) {
            const float4 wv4 = *(const float4*)(rw + ((d4 ^ swz) << 2));
            const float4 sv4 = *(const float4*)(&sS[(q << 7) + (d4 << 2)]);
            acc2 = fmaf(sv4.x, wv4.x, acc2);
            acc2 = fmaf(sv4.y, wv4.y, acc2);
            acc2 = fmaf(sv4.z, wv4.z, acc2);
            acc2 = fmaf(sv4.w, wv4.w, acc2);
        }
    }
    sB[(q << 7) + m] = acc2;

    __syncthreads();   // B4: Wc1T staged, sB visible, W2T reads done
    stage_lin<8>(sLo, ws + WS_WC2T, t);  // Wc2^T -> lo (under stage-2)

    // ---- Stage 2: t1 = silu(magg@Wc1 + bc1)
    acc2 = bc1k;
    {
        const float* rw = sHi + m * 128;
        #pragma unroll 8
        for (int d4 = 0; d4 < 32; ++d4) {
            const float4 wv4 = *(const float4*)(rw + ((d4 ^ swz) << 2));
            const float4 sv4 = *(const float4*)(&sB[(q << 7) + (d4 << 2)]);
            acc2 = fmaf(sv4.x, wv4.x, acc2);
            acc2 = fmaf(sv4.y, wv4.y, acc2);
            acc2 = fmaf(sv4.z, wv4.z, acc2);
            acc2 = fmaf(sv4.w, wv4.w, acc2);
        }
    }
    sS[(q << 7) + m] = silu_f(acc2);   // overwrite S with t1 (S consumed pre-B4)

    __syncthreads();   // B5: Wc2T staged, t1 visible, Wc1T reads done

    // ---- Stage 3: out = t1@Wc2 + bc2
    acc2 = bc2k;
    {
        const float* rw = sLo + m * 128;
        #pragma unroll 8
        for (int d4 = 0; d4 < 32; ++d4) {
            const float4 wv4 = *(const float4*)(rw + ((d4 ^ swz) << 2));
            const float4 sv4 = *(const float4*)(&sS[(q << 7) + (d4 << 2)]);
            acc2 = fmaf(sv4.x, wv4.x, acc2);
            acc2 = fmaf(sv4.y, wv4.y, acc2);
            acc2 = fmaf(sv4.z, wv4.z, acc2);
            acc2 = fmaf(sv4.w, wv4.w, acc2);
        }
    }
    out[(size_t)row0 * CC + t] = acc2;   // coalesced
}

extern "C" void kernel_launch(void* const* d_in, const int* in_sizes, int n_in,
                              void* d_out, int out_size, void* d_ws, size_t ws_size,
                              hipStream_t stream) {
    const float* h   = (const float*)d_in[0];
    const float* adj = (const float*)d_in[1];
    const float* W1a = (const float*)d_in[2];
    const float* W1b = (const float*)d_in[3];
    const float* b1  = (const float*)d_in[4];
    const float* W2  = (const float*)d_in[5];
    const float* b2  = (const float*)d_in[6];
    const float* Wc1 = (const float*)d_in[7];
    const float* bc1 = (const float*)d_in[8];
    const float* Wc2 = (const float*)d_in[9];
    const float* bc2 = (const float*)d_in[10];
    float* out = (float*)d_out;
    float* ws  = (float*)d_ws;

    k_proj<<<NBLK, TPB, 0, stream>>>(h, W1a, W1b, b1, W2, Wc1, Wc2, ws);
    k_msgout<<<NBLK, TPB, 0, stream>>>(adj, b2, bc1, bc2, ws, out);
}

// Round 6
// 96.502 us; speedup vs baseline: 2.0585x; 1.0119x over previous
//
#include <hip/hip_runtime.h>
#include <math.h>

// Shapes from reference: B=4, N=256, D=128, M=128, C=128
#define BB 4
#define NN 256
#define DD 128
#define MM 128
#define CC 128
#define ROWS (BB * NN)     // 1024
#define RPB 4              // rows per block
#define NBLK (ROWS / RPB)  // 256 blocks (== CU count, 1 block/CU)
#define TPB 512            // 8 waves

#define L2E 1.44269504088896340736f

// Workspace float offsets
#define WS_PIB   0          // pibias [1024][128]
#define WS_PJLO  131072     // pjT lo-half [4][128 m][128 j<128] (pre-swizzled)
#define WS_PJHI  196608     // pjT hi-half [4][128 m][128 j>=128]
#define WS_W2T   262144     // W2^T  [128][128] (pre-swizzled)
#define WS_WC1T  278528     // Wc1^T
#define WS_WC2T  294912     // Wc2^T

static __device__ __forceinline__ float fast_exp2(float x) {
#if __has_builtin(__builtin_amdgcn_exp2f)
    return __builtin_amdgcn_exp2f(x);
#else
    return __exp2f(x);
#endif
}

static __device__ __forceinline__ float fast_rcp(float x) {
#if __has_builtin(__builtin_amdgcn_rcpf)
    return __builtin_amdgcn_rcpf(x);
#else
    return 1.0f / x;
#endif
}

// silu(x) = x / (1 + exp(-x))
static __device__ __forceinline__ float silu_f(float x) {
    float e = fast_exp2(-L2E * x);
    return x * fast_rcp(1.0f + e);
}

#if __has_builtin(__builtin_amdgcn_global_load_lds)
#define HAS_GLDS 1
#define GLDS(gp, lp)                                                        \
    __builtin_amdgcn_global_load_lds(                                       \
        (const __attribute__((address_space(1))) void*)(gp),                \
        (__attribute__((address_space(3))) void*)(lp), 16, 0, 0)
#else
#define HAS_GLDS 0
#endif

// Linear burst stage: ITERS * 8 waves * 1KB chunks (source already laid out /
// pre-swizzled in global; LDS image == byte copy of source).
template <int ITERS>
static __device__ __forceinline__ void stage_lin(float* lds, const float* g,
                                                 int t) {
#if HAS_GLDS
    const int wv = t >> 6, lane = t & 63;
    #pragma unroll
    for (int i = 0; i < ITERS; ++i) {
        const int c = i * 8 + wv;              // 256-float chunk id
        GLDS(g + (size_t)c * 256 + lane * 4, lds + c * 256);
    }
#else
    #pragma unroll
    for (int i = 0; i < ITERS; ++i)
        ((float4*)lds)[i * TPB + t] = ((const float4*)g)[i * TPB + t];
#endif
}

// ---------------------------------------------------------------------------
// Kernel A: pibias = h@W1a + b1 ; pjT = (h@W1b)^T (pre-swizzled scatter).
// NO weight LDS: thread (m = t&127, X = mat, dup = d-half) reads each W value
// exactly once per CU via coalesced global b32 (L2-resident), accumulates
// partials for ALL 4 rows against broadcast h (2 KB LDS), then combines the
// two d-halves through a 20 KB sRed buffer. Blocks 0-11 also transpose
// W2/Wc1/Wc2 (pre-swizzled) into workspace for k_msgout Phase B.
// ---------------------------------------------------------------------------
__global__ __launch_bounds__(TPB) void k_proj(const float* __restrict__ h,
                                              const float* __restrict__ W1a,
                                              const float* __restrict__ W1b,
                                              const float* __restrict__ b1,
                                              const float* __restrict__ W2,
                                              const float* __restrict__ Wc1,
                                              const float* __restrict__ Wc2,
                                              float* __restrict__ ws) {
    __shared__ __align__(16) float sH[RPB * DD];   // 2 KB
    __shared__ __align__(16) float sRed[256 * 20]; // 20 KB: (X,m) rows of 20

    const int t = threadIdx.x;
    const int m   = t & 127;
    const int X   = (t >> 7) & 1;   // 0: W1a, 1: W1b   (wave-uniform)
    const int dup = t >> 8;         // d-half            (wave-uniform)
    const int row0 = blockIdx.x * RPB;

    sH[t] = h[(size_t)row0 * DD + t];
    const float* __restrict__ Wp = X ? W1b : W1a;
    const float bias = b1[m];
    __syncthreads();                 // sH visible

    const int d0 = dup * 64;
    float a0 = 0.f, a1 = 0.f, a2 = 0.f, a3 = 0.f;
    #pragma unroll 4
    for (int c = 0; c < 16; ++c) {
        const int d = d0 + c * 4;
        // coalesced global loads (L2-hit after first touch), 1 per value/CU
        const float w0 = Wp[(size_t)(d + 0) * MM + m];
        const float w1 = Wp[(size_t)(d + 1) * MM + m];
        const float w2 = Wp[(size_t)(d + 2) * MM + m];
        const float w3 = Wp[(size_t)(d + 3) * MM + m];
        // broadcast h chunks for all 4 rows (wave-uniform b128)
        const float4 h0 = *(const float4*)&sH[0 * DD + d];
        const float4 h1 = *(const float4*)&sH[1 * DD + d];
        const float4 h2 = *(const float4*)&sH[2 * DD + d];
        const float4 h3 = *(const float4*)&sH[3 * DD + d];
        a0 = fmaf(h0.x, w0, a0); a0 = fmaf(h0.y, w1, a0);
        a0 = fmaf(h0.z, w2, a0); a0 = fmaf(h0.w, w3, a0);
        a1 = fmaf(h1.x, w0, a1); a1 = fmaf(h1.y, w1, a1);
        a1 = fmaf(h1.z, w2, a1); a1 = fmaf(h1.w, w3, a1);
        a2 = fmaf(h2.x, w0, a2); a2 = fmaf(h2.y, w1, a2);
        a2 = fmaf(h2.z, w2, a2); a2 = fmaf(h2.w, w3, a2);
        a3 = fmaf(h3.x, w0, a3); a3 = fmaf(h3.y, w1, a3);
        a3 = fmaf(h3.z, w2, a3); a3 = fmaf(h3.w, w3, a3);
    }
    {
        float4 pv; pv.x = a0; pv.y = a1; pv.z = a2; pv.w = a3;
        *(float4*)&sRed[((X << 7) | m) * 20 + dup * 8] = pv;  // 16B-aligned
    }
    __syncthreads();                 // partials visible

    // Combine: this thread finishes rows q = 2*dup, 2*dup+1 for its (X,m).
    {
        const int base = ((X << 7) | m) * 20;
        #pragma unroll
        for (int k = 0; k < 2; ++k) {
            const int q = 2 * dup + k;
            const float v = sRed[base + q] + sRed[base + 8 + q];
            if (X == 0) {            // wave-uniform branch
                ws[WS_PIB + (size_t)(row0 + q) * MM + m] = v + bias;
            } else {
                // pjT pre-swizzled scatter: pjT[m][jloc], 16B slot ^= (m&7)
                const int b    = row0 >> 8;
                const int jloc = (row0 & 255) + q;
                const int half = jloc >> 7;
                const int jj   = jloc & 127;
                const int c16  = jj >> 2;
                const int off  = (half ? WS_PJHI : WS_PJLO) + b * 16384 +
                                 m * 128 + (((c16 ^ (m & 7)) << 2) | (jj & 3));
                ws[off] = v;
            }
        }
    }

    // Weight transposes (pre-swizzled): blocks 0-11, 32 d-rows each.
    if (blockIdx.x < 12) {
        const int blk = blockIdx.x;
        const int qq = t >> 7;       // 0..3
        const float* Wsrc = (blk < 4) ? W2 : (blk < 8) ? Wc1 : Wc2;
        float* Wdst = ws + ((blk < 4) ? WS_W2T : (blk < 8) ? WS_WC1T : WS_WC2T);
        const int d0t = (blk & 3) * 32;
        const int k = m;
        #pragma unroll
        for (int i = 0; i < 8; ++i) {
            const int d = d0t + (qq << 3) + i;
            const float v = Wsrc[(size_t)d * 128 + k];   // coalesced over k
            Wdst[k * 128 + ((((d >> 2) ^ (k & 7)) << 2) | (d & 3))] = v;
        }
    }
}

// ---------------------------------------------------------------------------
// Kernel B: fused msg + output head. 256 blocks x 512 threads, 4 rows/block.
// Phase A (unchanged, trans/VALU-floor): swizzled b128 pjT rows + uniform adj.
// Phase B partial-split: thread (q,m) reads only WT[m][32q..32q+32) (8 b128 --
// each weight value once per CU), computes partials for ALL 4 output rows,
// combines via sP. Weights staged under the previous phase's compute.
// ---------------------------------------------------------------------------
__global__ __launch_bounds__(TPB) void k_msgout(const float* __restrict__ adj,
                                                const float* __restrict__ b2,
                                                const float* __restrict__ bc1,
                                                const float* __restrict__ bc2,
                                                const float* __restrict__ ws,
                                                float* __restrict__ out) {
    __shared__ __align__(16) float sLo[16384];    // 64 KB: pjT lo / W2T / Wc2T
    __shared__ __align__(16) float sHi[16384];    // 64 KB: pjT hi / Wc1T
    __shared__ __align__(16) float sS[RPB * MM];  // S rows, later t1
    __shared__ __align__(16) float sB[RPB * MM];  // magg
    __shared__ __align__(16) float sP[128 * 20];  // 10 KB: stage partials
    __shared__ float sWr0[8], sWr1[8];

    const int t = threadIdx.x;
    const int blk = blockIdx.x;        // 256 blocks
    const int b = blk >> 6;            // batch
    const int i0 = (blk & 63) * RPB;   // first row (batch-local)
    const int row0 = b * NN + i0;

    const int m = t & 127;
    const int q = t >> 7;              // row within block (uniform per wave)
    const int w = t >> 6;              // wave id
    const int swz = m & 7;

    // ---- issue pjT staging (128 KB total, pre-swizzled source -> linear)
    stage_lin<8>(sLo, ws + WS_PJLO + b * 16384, t);
    stage_lin<8>(sHi, ws + WS_PJHI + b * 16384, t);

    // ---- early loads (overlap with staging)
    const float pim  = ws[WS_PIB + (size_t)row0 * MM + t];  // pibias[row0+q][m]
    const float b2k  = b2[m];
    const float bc1k = bc1[m];
    const float bc2k = bc2[m];

    // adj row sums via coalesced vector loads + wave shuffle
    const float* arow = adj + (size_t)row0 * NN;
    const float a0v = arow[t];          // rows 0/1
    const float a1v = arow[t + TPB];    // rows 2/3
    float v0 = a0v, v1 = a1v;
    #pragma unroll
    for (int off = 32; off > 0; off >>= 1) {
        v0 += __shfl_xor(v0, off, 64);
        v1 += __shfl_xor(v1, off, 64);
    }
    if ((t & 63) == 0) { sWr0[w] = v0; sWr1[w] = v1; }

    // wave-uniform adj row pointer (scalarized)
    const int srow = __builtin_amdgcn_readfirstlane(row0 + q);
    const float* __restrict__ adjr = adj + (size_t)srow * NN;

    __syncthreads();   // B1: pjT staged, sWr visible

    float A;
    {
        const int base = (q & 1) * 4;
        A = (q < 2) ? (sWr0[base] + sWr0[base + 1] + sWr0[base + 2] + sWr0[base + 3])
                    : (sWr1[base] + sWr1[base + 1] + sWr1[base + 2] + sWr1[base + 3]);
    }
    const float aii = adjr[srow & 255];     // diagonal (uniform scalar load)
    const float inv = 1.0f / fmaxf(A, 1.0f);
    const float bet = (A - aii) * inv;
    const float npim = -L2E * pim;

    // Diagonal correction (subtract instead of zeroing adj)
    float acc;
    {
        const int iloc = i0 + q;
        const int jj = iloc & 127;
        const float* base = (iloc < 128) ? sLo : sHi;
        const float pjd = base[m * 128 + ((((jj >> 2) ^ swz) << 2) | (jj & 3))];
        acc = -aii * silu_f(pim + pjd);
    }

    // ---- Phase A, j in [0,128): swizzled b128 rows of pjT-lo
    const float* rowLo = sLo + m * 128;
    #pragma unroll 8
    for (int j4 = 0; j4 < 32; ++j4) {
        const float4 pv = *(const float4*)(rowLo + ((j4 ^ swz) << 2));
        const float4 av = *(const float4*)(adjr + (j4 << 2));   // uniform
        const float x0 = pim + pv.x, x1 = pim + pv.y;
        const float x2 = pim + pv.z, x3 = pim + pv.w;
        const float e0 = fast_exp2(fmaf(-L2E, pv.x, npim));
        const float e1 = fast_exp2(fmaf(-L2E, pv.y, npim));
        const float e2 = fast_exp2(fmaf(-L2E, pv.z, npim));
        const float e3 = fast_exp2(fmaf(-L2E, pv.w, npim));
        const float d0 = 1.0f + e0, d1 = 1.0f + e1;
        const float d2 = 1.0f + e2, d3 = 1.0f + e3;
        const float r01 = fast_rcp(d0 * d1), r23 = fast_rcp(d2 * d3);
        acc = fmaf(av.x * x0, r01 * d1, acc);
        acc = fmaf(av.y * x1, r01 * d0, acc);
        acc = fmaf(av.z * x2, r23 * d3, acc);
        acc = fmaf(av.w * x3, r23 * d2, acc);
    }

    __syncthreads();   // B2: all lo reads done
    stage_lin<8>(sLo, ws + WS_W2T, t);   // W2^T -> lo (under hi compute)

    // ---- Phase A, j in [128,256)
    const float* rowHi = sHi + m * 128;
    #pragma unroll 8
    for (int j4 = 0; j4 < 32; ++j4) {
        const float4 pv = *(const float4*)(rowHi + ((j4 ^ swz) << 2));
        const float4 av = *(const float4*)(adjr + 128 + (j4 << 2));
        const float x0 = pim + pv.x, x1 = pim + pv.y;
        const float x2 = pim + pv.z, x3 = pim + pv.w;
        const float e0 = fast_exp2(fmaf(-L2E, pv.x, npim));
        const float e1 = fast_exp2(fmaf(-L2E, pv.y, npim));
        const float e2 = fast_exp2(fmaf(-L2E, pv.z, npim));
        const float e3 = fast_exp2(fmaf(-L2E, pv.w, npim));
        const float d0 = 1.0f + e0, d1 = 1.0f + e1;
        const float d2 = 1.0f + e2, d3 = 1.0f + e3;
        const float r01 = fast_rcp(d0 * d1), r23 = fast_rcp(d2 * d3);
        acc = fmaf(av.x * x0, r01 * d1, acc);
        acc = fmaf(av.y * x1, r01 * d0, acc);
        acc = fmaf(av.z * x2, r23 * d3, acc);
        acc = fmaf(av.w * x3, r23 * d2, acc);
    }
    sS[(q << 7) + m] = acc * inv;

    __syncthreads();   // B3: W2T staged, sS visible, hi reads done
    stage_lin<8>(sHi, ws + WS_WC1T, t);  // Wc1^T -> hi (under stage-1)

    // ================= Phase B: partial-split stages =====================
    // Stage partial macro-shape: thread (q,m) covers d in [32q, 32q+32),
    // weights: 8 owned b128 from WT[m]; vector operand: uniform b128.

    // ---- Stage 1 partials: magg = S@W2 (+ beta*b2 at combine)
    {
        const float* rw = sLo + m * 128;
        float p0 = 0.f, p1 = 0.f, p2 = 0.f, p3 = 0.f;
        #pragma unroll
        for (int i = 0; i < 8; ++i) {
            const int d4 = (q << 3) + i;
            const float4 wv4 = *(const float4*)(rw + ((d4 ^ swz) << 2));
            const float4 s0 = *(const float4*)(&sS[(0 << 7) + (d4 << 2)]);
            const float4 s1 = *(const float4*)(&sS[(1 << 7) + (d4 << 2)]);
            const float4 s2 = *(const float4*)(&sS[(2 << 7) + (d4 << 2)]);
            const float4 s3 = *(const float4*)(&sS[(3 << 7) + (d4 << 2)]);
            p0 = fmaf(s0.x, wv4.x, p0); p0 = fmaf(s0.y, wv4.y, p0);
            p0 = fmaf(s0.z, wv4.z, p0); p0 = fmaf(s0.w, wv4.w, p0);
            p1 = fmaf(s1.x, wv4.x, p1); p1 = fmaf(s1.y, wv4.y, p1);
            p1 = fmaf(s1.z, wv4.z, p1); p1 = fmaf(s1.w, wv4.w, p1);
            p2 = fmaf(s2.x, wv4.x, p2); p2 = fmaf(s2.y, wv4.y, p2);
            p2 = fmaf(s2.z, wv4.z, p2); p2 = fmaf(s2.w, wv4.w, p2);
            p3 = fmaf(s3.x, wv4.x, p3); p3 = fmaf(s3.y, wv4.y, p3);
            p3 = fmaf(s3.z, wv4.z, p3); p3 = fmaf(s3.w, wv4.w, p3);
        }
        float4 pv; pv.x = p0; pv.y = p1; pv.z = p2; pv.w = p3;
        *(float4*)&sP[m * 20 + (q << 2)] = pv;
    }
    __syncthreads();   // B4: sP visible; Wc1T staged (was in flight)

    // combine1 -> sB (magg row q)
    {
        const int base = m * 20 + q;
        const float mg = sP[base] + sP[base + 4] + sP[base + 8] + sP[base + 12]
                         + bet * b2k;
        sB[(q << 7) + m] = mg;
    }
    __syncthreads();   // B4b: sB visible
    stage_lin<8>(sLo, ws + WS_WC2T, t);  // Wc2^T -> lo (under stage-2)

    // ---- Stage 2 partials: t1 = silu(magg@Wc1 + bc1)
    {
        const float* rw = sHi + m * 128;
        float p0 = 0.f, p1 = 0.f, p2 = 0.f, p3 = 0.f;
        #pragma unroll
        for (int i = 0; i < 8; ++i) {
            const int d4 = (q << 3) + i;
            const float4 wv4 = *(const float4*)(rw + ((d4 ^ swz) << 2));
            const float4 s0 = *(const float4*)(&sB[(0 << 7) + (d4 << 2)]);
            const float4 s1 = *(const float4*)(&sB[(1 << 7) + (d4 << 2)]);
            const float4 s2 = *(const float4*)(&sB[(2 << 7) + (d4 << 2)]);
            const float4 s3 = *(const float4*)(&sB[(3 << 7) + (d4 << 2)]);
            p0 = fmaf(s0.x, wv4.x, p0); p0 = fmaf(s0.y, wv4.y, p0);
            p0 = fmaf(s0.z, wv4.z, p0); p0 = fmaf(s0.w, wv4.w, p0);
            p1 = fmaf(s1.x, wv4.x, p1); p1 = fmaf(s1.y, wv4.y, p1);
            p1 = fmaf(s1.z, wv4.z, p1); p1 = fmaf(s1.w, wv4.w, p1);
            p2 = fmaf(s2.x, wv4.x, p2); p2 = fmaf(s2.y, wv4.y, p2);
            p2 = fmaf(s2.z, wv4.z, p2); p2 = fmaf(s2.w, wv4.w, p2);
            p3 = fmaf(s3.x, wv4.x, p3); p3 = fmaf(s3.y, wv4.y, p3);
            p3 = fmaf(s3.z, wv4.z, p3); p3 = fmaf(s3.w, wv4.w, p3);
        }
        float4 pv; pv.x = p0; pv.y = p1; pv.z = p2; pv.w = p3;
        *(float4*)&sP[m * 20 + (q << 2)] = pv;
    }
    __syncthreads();   // B5: sP visible; Wc2T staged

    // combine2 -> sS (t1 row q); stage-1 sS readers finished before B4
    {
        const int base = m * 20 + q;
        const float tv = sP[base] + sP[base + 4] + sP[base + 8] + sP[base + 12]
                         + bc1k;
        sS[(q << 7) + m] = silu_f(tv);
    }
    __syncthreads();   // B5b: t1 visible

    // ---- Stage 3 partials: out = t1@Wc2 + bc2
    {
        const float* rw = sLo + m * 128;
        float p0 = 0.f, p1 = 0.f, p2 = 0.f, p3 = 0.f;
        #pragma unroll
        for (int i = 0; i < 8; ++i) {
            const int d4 = (q << 3) + i;
            const float4 wv4 = *(const float4*)(rw + ((d4 ^ swz) << 2));
            const float4 s0 = *(const float4*)(&sS[(0 << 7) + (d4 << 2)]);
            const float4 s1 = *(const float4*)(&sS[(1 << 7) + (d4 << 2)]);
            const float4 s2 = *(const float4*)(&sS[(2 << 7) + (d4 << 2)]);
            const float4 s3 = *(const float4*)(&sS[(3 << 7) + (d4 << 2)]);
            p0 = fmaf(s0.x, wv4.x, p0); p0 = fmaf(s0.y, wv4.y, p0);
            p0 = fmaf(s0.z, wv4.z, p0); p0 = fmaf(s0.w, wv4.w, p0);
            p1 = fmaf(s1.x, wv4.x, p1); p1 = fmaf(s1.y, wv4.y, p1);
            p1 = fmaf(s1.z, wv4.z, p1); p1 = fmaf(s1.w, wv4.w, p1);
            p2 = fmaf(s2.x, wv4.x, p2); p2 = fmaf(s2.y, wv4.y, p2);
            p2 = fmaf(s2.z, wv4.z, p2); p2 = fmaf(s2.w, wv4.w, p2);
            p3 = fmaf(s3.x, wv4.x, p3); p3 = fmaf(s3.y, wv4.y, p3);
            p3 = fmaf(s3.z, wv4.z, p3); p3 = fmaf(s3.w, wv4.w, p3);
        }
        float4 pv; pv.x = p0; pv.y = p1; pv.z = p2; pv.w = p3;
        *(float4*)&sP[m * 20 + (q << 2)] = pv;
    }
    __syncthreads();   // B6: sP visible

    // combine3 -> global store (coalesced: (row0+q)*CC + m == row0*CC + t)
    {
        const int base = m * 20 + q;
        const float ov = sP[base] + sP[base + 4] + sP[base + 8] + sP[base + 12]
                         + bc2k;
        out[(size_t)row0 * CC + t] = ov;
    }
}

extern "C" void kernel_launch(void* const* d_in, const int* in_sizes, int n_in,
                              void* d_out, int out_size, void* d_ws, size_t ws_size,
                              hipStream_t stream) {
    const float* h   = (const float*)d_in[0];
    const float* adj = (const float*)d_in[1];
    const float* W1a = (const float*)d_in[2];
    const float* W1b = (const float*)d_in[3];
    const float* b1  = (const float*)d_in[4];
    const float* W2  = (const float*)d_in[5];
    const float* b2  = (const float*)d_in[6];
    const float* Wc1 = (const float*)d_in[7];
    const float* bc1 = (const float*)d_in[8];
    const float* Wc2 = (const float*)d_in[9];
    const float* bc2 = (const float*)d_in[10];
    float* out = (float*)d_out;
    float* ws  = (float*)d_ws;

    k_proj<<<NBLK, TPB, 0, stream>>>(h, W1a, W1b, b1, W2, Wc1, Wc2, ws);
    k_msgout<<<NBLK, TPB, 0, stream>>>(adj, b2, bc1, bc2, ws, out);
}

// Round 7
// 95.254 us; speedup vs baseline: 2.0855x; 1.0131x over previous
//
#include <hip/hip_runtime.h>
#include <math.h>

// Shapes from reference: B=4, N=256, D=128, M=128, C=128
#define BB 4
#define NN 256
#define DD 128
#define MM 128
#define CC 128
#define ROWS (BB * NN)     // 1024
#define RPB 4              // rows per block
#define NBLK (ROWS / RPB)  // 256 blocks (== CU count, 1 block/CU)
#define TPB 512            // 8 waves

#define L2E 1.44269504088896340736f

// Workspace float offsets
#define WS_PIB   0          // pibias [1024][128]
#define WS_PJLO  131072     // pjT lo-half [4][128 m][128 j<128] (pre-swizzled)
#define WS_PJHI  196608     // pjT hi-half [4][128 m][128 j>=128]
#define WS_W2T   262144     // W2^T  [128][128] (pre-swizzled)
#define WS_WC1T  278528     // Wc1^T
#define WS_WC2T  294912     // Wc2^T

static __device__ __forceinline__ float fast_exp2(float x) {
#if __has_builtin(__builtin_amdgcn_exp2f)
    return __builtin_amdgcn_exp2f(x);
#else
    return __exp2f(x);
#endif
}

static __device__ __forceinline__ float fast_rcp(float x) {
#if __has_builtin(__builtin_amdgcn_rcpf)
    return __builtin_amdgcn_rcpf(x);
#else
    return 1.0f / x;
#endif
}

// silu(x) = x / (1 + exp(-x))
static __device__ __forceinline__ float silu_f(float x) {
    float e = fast_exp2(-L2E * x);
    return x * fast_rcp(1.0f + e);
}

#if __has_builtin(__builtin_amdgcn_global_load_lds)
#define HAS_GLDS 1
#define GLDS(gp, lp)                                                        \
    __builtin_amdgcn_global_load_lds(                                       \
        (const __attribute__((address_space(1))) void*)(gp),                \
        (__attribute__((address_space(3))) void*)(lp), 16, 0, 0)
#else
#define HAS_GLDS 0
#endif

// Linear burst stage: ITERS * 8 waves * 1KB chunks (source already laid out /
// pre-swizzled in global; LDS image == byte copy of source).
template <int ITERS>
static __device__ __forceinline__ void stage_lin(float* lds, const float* g,
                                                 int t) {
#if HAS_GLDS
    const int wv = t >> 6, lane = t & 63;
    #pragma unroll
    for (int i = 0; i < ITERS; ++i) {
        const int c = i * 8 + wv;              // 256-float chunk id
        GLDS(g + (size_t)c * 256 + lane * 4, lds + c * 256);
    }
#else
    #pragma unroll
    for (int i = 0; i < ITERS; ++i)
        ((float4*)lds)[i * TPB + t] = ((const float4*)g)[i * TPB + t];
#endif
}

// ---------------------------------------------------------------------------
// Kernel A: pibias = h@W1a + b1 ; pjT = (h@W1b)^T (pre-swizzled scatter).
// NO weight LDS: thread (m = t&127, X = mat, dup = d-half) reads each W value
// exactly once per CU via coalesced global b32 (L2-resident), accumulates
// partials for ALL 4 rows against broadcast h (2 KB LDS), then combines the
// two d-halves through a 20 KB sRed buffer. Blocks 0-11 also transpose
// W2/Wc1/Wc2 (pre-swizzled) into workspace for k_msgout Phase B.
// ---------------------------------------------------------------------------
__global__ __launch_bounds__(TPB) void k_proj(const float* __restrict__ h,
                                              const float* __restrict__ W1a,
                                              const float* __restrict__ W1b,
                                              const float* __restrict__ b1,
                                              const float* __restrict__ W2,
                                              const float* __restrict__ Wc1,
                                              const float* __restrict__ Wc2,
                                              float* __restrict__ ws) {
    __shared__ __align__(16) float sH[RPB * DD];   // 2 KB
    __shared__ __align__(16) float sRed[256 * 20]; // 20 KB: (X,m) rows of 20

    const int t = threadIdx.x;
    const int m   = t & 127;
    const int X   = (t >> 7) & 1;   // 0: W1a, 1: W1b   (wave-uniform)
    const int dup = t >> 8;         // d-half            (wave-uniform)
    const int row0 = blockIdx.x * RPB;

    sH[t] = h[(size_t)row0 * DD + t];
    const float* __restrict__ Wp = X ? W1b : W1a;
    const float bias = b1[m];
    __syncthreads();                 // sH visible

    const int d0 = dup * 64;
    float a0 = 0.f, a1 = 0.f, a2 = 0.f, a3 = 0.f;
    #pragma unroll 4
    for (int c = 0; c < 16; ++c) {
        const int d = d0 + c * 4;
        // coalesced global loads (L2-hit after first touch), 1 per value/CU
        const float w0 = Wp[(size_t)(d + 0) * MM + m];
        const float w1 = Wp[(size_t)(d + 1) * MM + m];
        const float w2 = Wp[(size_t)(d + 2) * MM + m];
        const float w3 = Wp[(size_t)(d + 3) * MM + m];
        // broadcast h chunks for all 4 rows (wave-uniform b128)
        const float4 h0 = *(const float4*)&sH[0 * DD + d];
        const float4 h1 = *(const float4*)&sH[1 * DD + d];
        const float4 h2 = *(const float4*)&sH[2 * DD + d];
        const float4 h3 = *(const float4*)&sH[3 * DD + d];
        a0 = fmaf(h0.x, w0, a0); a0 = fmaf(h0.y, w1, a0);
        a0 = fmaf(h0.z, w2, a0); a0 = fmaf(h0.w, w3, a0);
        a1 = fmaf(h1.x, w0, a1); a1 = fmaf(h1.y, w1, a1);
        a1 = fmaf(h1.z, w2, a1); a1 = fmaf(h1.w, w3, a1);
        a2 = fmaf(h2.x, w0, a2); a2 = fmaf(h2.y, w1, a2);
        a2 = fmaf(h2.z, w2, a2); a2 = fmaf(h2.w, w3, a2);
        a3 = fmaf(h3.x, w0, a3); a3 = fmaf(h3.y, w1, a3);
        a3 = fmaf(h3.z, w2, a3); a3 = fmaf(h3.w, w3, a3);
    }
    {
        float4 pv; pv.x = a0; pv.y = a1; pv.z = a2; pv.w = a3;
        *(float4*)&sRed[((X << 7) | m) * 20 + dup * 8] = pv;  // 16B-aligned
    }
    __syncthreads();                 // partials visible

    // Combine: this thread finishes rows q = 2*dup, 2*dup+1 for its (X,m).
    {
        const int base = ((X << 7) | m) * 20;
        #pragma unroll
        for (int k = 0; k < 2; ++k) {
            const int q = 2 * dup + k;
            const float v = sRed[base + q] + sRed[base + 8 + q];
            if (X == 0) {            // wave-uniform branch
                ws[WS_PIB + (size_t)(row0 + q) * MM + m] = v + bias;
            } else {
                // pjT pre-swizzled scatter: pjT[m][jloc], 16B slot ^= (m&7)
                const int b    = row0 >> 8;
                const int jloc = (row0 & 255) + q;
                const int half = jloc >> 7;
                const int jj   = jloc & 127;
                const int c16  = jj >> 2;
                const int off  = (half ? WS_PJHI : WS_PJLO) + b * 16384 +
                                 m * 128 + (((c16 ^ (m & 7)) << 2) | (jj & 3));
                ws[off] = v;
            }
        }
    }

    // Weight transposes (pre-swizzled): blocks 0-11, 32 d-rows each.
    if (blockIdx.x < 12) {
        const int blk = blockIdx.x;
        const int qq = t >> 7;       // 0..3
        const float* Wsrc = (blk < 4) ? W2 : (blk < 8) ? Wc1 : Wc2;
        float* Wdst = ws + ((blk < 4) ? WS_W2T : (blk < 8) ? WS_WC1T : WS_WC2T);
        const int d0t = (blk & 3) * 32;
        const int k = m;
        #pragma unroll
        for (int i = 0; i < 8; ++i) {
            const int d = d0t + (qq << 3) + i;
            const float v = Wsrc[(size_t)d * 128 + k];   // coalesced over k
            Wdst[k * 128 + ((((d >> 2) ^ (k & 7)) << 2) | (d & 3))] = v;
        }
    }
}

// ---------------------------------------------------------------------------
// Kernel B: fused msg + output head. 256 blocks x 512 threads, 4 rows/block.
// Phase A: swizzled b128 pjT rows + uniform adj, FOUR independent
// accumulators (breaks the 256-deep serial fmac chain -- the last remaining
// dependency-latency bottleneck at 2 waves/SIMD).
// Phase B partial-split: thread (q,m) reads only WT[m][32q..32q+32) (8 b128 --
// each weight value once per CU), computes partials for ALL 4 output rows,
// combines via sP. Weights staged under the previous phase's compute.
// ---------------------------------------------------------------------------
__global__ __launch_bounds__(TPB) void k_msgout(const float* __restrict__ adj,
                                                const float* __restrict__ b2,
                                                const float* __restrict__ bc1,
                                                const float* __restrict__ bc2,
                                                const float* __restrict__ ws,
                                                float* __restrict__ out) {
    __shared__ __align__(16) float sLo[16384];    // 64 KB: pjT lo / W2T / Wc2T
    __shared__ __align__(16) float sHi[16384];    // 64 KB: pjT hi / Wc1T
    __shared__ __align__(16) float sS[RPB * MM];  // S rows, later t1
    __shared__ __align__(16) float sB[RPB * MM];  // magg
    __shared__ __align__(16) float sP[128 * 20];  // 10 KB: stage partials
    __shared__ float sWr0[8], sWr1[8];

    const int t = threadIdx.x;
    const int blk = blockIdx.x;        // 256 blocks
    const int b = blk >> 6;            // batch
    const int i0 = (blk & 63) * RPB;   // first row (batch-local)
    const int row0 = b * NN + i0;

    const int m = t & 127;
    const int q = t >> 7;              // row within block (uniform per wave)
    const int w = t >> 6;              // wave id
    const int swz = m & 7;

    // ---- issue pjT staging (128 KB total, pre-swizzled source -> linear)
    stage_lin<8>(sLo, ws + WS_PJLO + b * 16384, t);
    stage_lin<8>(sHi, ws + WS_PJHI + b * 16384, t);

    // ---- early loads (overlap with staging)
    const float pim  = ws[WS_PIB + (size_t)row0 * MM + t];  // pibias[row0+q][m]
    const float b2k  = b2[m];
    const float bc1k = bc1[m];
    const float bc2k = bc2[m];

    // adj row sums via coalesced vector loads + wave shuffle
    const float* arow = adj + (size_t)row0 * NN;
    const float a0v = arow[t];          // rows 0/1
    const float a1v = arow[t + TPB];    // rows 2/3
    float v0 = a0v, v1 = a1v;
    #pragma unroll
    for (int off = 32; off > 0; off >>= 1) {
        v0 += __shfl_xor(v0, off, 64);
        v1 += __shfl_xor(v1, off, 64);
    }
    if ((t & 63) == 0) { sWr0[w] = v0; sWr1[w] = v1; }

    // wave-uniform adj row pointer (scalarized)
    const int srow = __builtin_amdgcn_readfirstlane(row0 + q);
    const float* __restrict__ adjr = adj + (size_t)srow * NN;

    __syncthreads();   // B1: pjT staged, sWr visible

    float A;
    {
        const int base = (q & 1) * 4;
        A = (q < 2) ? (sWr0[base] + sWr0[base + 1] + sWr0[base + 2] + sWr0[base + 3])
                    : (sWr1[base] + sWr1[base + 1] + sWr1[base + 2] + sWr1[base + 3]);
    }
    const float aii = adjr[srow & 255];     // diagonal (uniform scalar load)
    const float inv = 1.0f / fmaxf(A, 1.0f);
    const float bet = (A - aii) * inv;
    const float npim = -L2E * pim;

    // Diagonal correction (subtract instead of zeroing adj)
    float dcorr;
    {
        const int iloc = i0 + q;
        const int jj = iloc & 127;
        const float* base = (iloc < 128) ? sLo : sHi;
        const float pjd = base[m * 128 + ((((jj >> 2) ^ swz) << 2) | (jj & 3))];
        dcorr = -aii * silu_f(pim + pjd);
    }

    // ---- Phase A: 4 INDEPENDENT accumulators (no serial fmac chain)
    float ac0 = dcorr, ac1 = 0.f, ac2 = 0.f, ac3 = 0.f;

    // j in [0,128): swizzled b128 rows of pjT-lo
    const float* rowLo = sLo + m * 128;
    #pragma unroll 8
    for (int j4 = 0; j4 < 32; ++j4) {
        const float4 pv = *(const float4*)(rowLo + ((j4 ^ swz) << 2));
        const float4 av = *(const float4*)(adjr + (j4 << 2));   // uniform
        const float x0 = pim + pv.x, x1 = pim + pv.y;
        const float x2 = pim + pv.z, x3 = pim + pv.w;
        const float e0 = fast_exp2(fmaf(-L2E, pv.x, npim));
        const float e1 = fast_exp2(fmaf(-L2E, pv.y, npim));
        const float e2 = fast_exp2(fmaf(-L2E, pv.z, npim));
        const float e3 = fast_exp2(fmaf(-L2E, pv.w, npim));
        const float d0 = 1.0f + e0, d1 = 1.0f + e1;
        const float d2 = 1.0f + e2, d3 = 1.0f + e3;
        const float r01 = fast_rcp(d0 * d1), r23 = fast_rcp(d2 * d3);
        ac0 = fmaf(av.x * x0, r01 * d1, ac0);
        ac1 = fmaf(av.y * x1, r01 * d0, ac1);
        ac2 = fmaf(av.z * x2, r23 * d3, ac2);
        ac3 = fmaf(av.w * x3, r23 * d2, ac3);
    }

    __syncthreads();   // B2: all lo reads done
    stage_lin<8>(sLo, ws + WS_W2T, t);   // W2^T -> lo (under hi compute)

    // ---- Phase A, j in [128,256)
    const float* rowHi = sHi + m * 128;
    #pragma unroll 8
    for (int j4 = 0; j4 < 32; ++j4) {
        const float4 pv = *(const float4*)(rowHi + ((j4 ^ swz) << 2));
        const float4 av = *(const float4*)(adjr + 128 + (j4 << 2));
        const float x0 = pim + pv.x, x1 = pim + pv.y;
        const float x2 = pim + pv.z, x3 = pim + pv.w;
        const float e0 = fast_exp2(fmaf(-L2E, pv.x, npim));
        const float e1 = fast_exp2(fmaf(-L2E, pv.y, npim));
        const float e2 = fast_exp2(fmaf(-L2E, pv.z, npim));
        const float e3 = fast_exp2(fmaf(-L2E, pv.w, npim));
        const float d0 = 1.0f + e0, d1 = 1.0f + e1;
        const float d2 = 1.0f + e2, d3 = 1.0f + e3;
        const float r01 = fast_rcp(d0 * d1), r23 = fast_rcp(d2 * d3);
        ac0 = fmaf(av.x * x0, r01 * d1, ac0);
        ac1 = fmaf(av.y * x1, r01 * d0, ac1);
        ac2 = fmaf(av.z * x2, r23 * d3, ac2);
        ac3 = fmaf(av.w * x3, r23 * d2, ac3);
    }
    sS[(q << 7) + m] = ((ac0 + ac1) + (ac2 + ac3)) * inv;

    __syncthreads();   // B3: W2T staged, sS visible, hi reads done
    stage_lin<8>(sHi, ws + WS_WC1T, t);  // Wc1^T -> hi (under stage-1)

    // ================= Phase B: partial-split stages =====================
    // Stage partial macro-shape: thread (q,m) covers d in [32q, 32q+32),
    // weights: 8 owned b128 from WT[m]; vector operand: uniform b128.

    // ---- Stage 1 partials: magg = S@W2 (+ beta*b2 at combine)
    {
        const float* rw = sLo + m * 128;
        float p0 = 0.f, p1 = 0.f, p2 = 0.f, p3 = 0.f;
        #pragma unroll
        for (int i = 0; i < 8; ++i) {
            const int d4 = (q << 3) + i;
            const float4 wv4 = *(const float4*)(rw + ((d4 ^ swz) << 2));
            const float4 s0 = *(const float4*)(&sS[(0 << 7) + (d4 << 2)]);
            const float4 s1 = *(const float4*)(&sS[(1 << 7) + (d4 << 2)]);
            const float4 s2 = *(const float4*)(&sS[(2 << 7) + (d4 << 2)]);
            const float4 s3 = *(const float4*)(&sS[(3 << 7) + (d4 << 2)]);
            p0 = fmaf(s0.x, wv4.x, p0); p0 = fmaf(s0.y, wv4.y, p0);
            p0 = fmaf(s0.z, wv4.z, p0); p0 = fmaf(s0.w, wv4.w, p0);
            p1 = fmaf(s1.x, wv4.x, p1); p1 = fmaf(s1.y, wv4.y, p1);
            p1 = fmaf(s1.z, wv4.z, p1); p1 = fmaf(s1.w, wv4.w, p1);
            p2 = fmaf(s2.x, wv4.x, p2); p2 = fmaf(s2.y, wv4.y, p2);
            p2 = fmaf(s2.z, wv4.z, p2); p2 = fmaf(s2.w, wv4.w, p2);
            p3 = fmaf(s3.x, wv4.x, p3); p3 = fmaf(s3.y, wv4.y, p3);
            p3 = fmaf(s3.z, wv4.z, p3); p3 = fmaf(s3.w, wv4.w, p3);
        }
        float4 pv; pv.x = p0; pv.y = p1; pv.z = p2; pv.w = p3;
        *(float4*)&sP[m * 20 + (q << 2)] = pv;
    }
    __syncthreads();   // B4: sP visible; Wc1T staged (was in flight)

    // combine1 -> sB (magg row q)
    {
        const int base = m * 20 + q;
        const float mg = sP[base] + sP[base + 4] + sP[base + 8] + sP[base + 12]
                         + bet * b2k;
        sB[(q << 7) + m] = mg;
    }
    __syncthreads();   // B4b: sB visible
    stage_lin<8>(sLo, ws + WS_WC2T, t);  // Wc2^T -> lo (under stage-2)

    // ---- Stage 2 partials: t1 = silu(magg@Wc1 + bc1)
    {
        const float* rw = sHi + m * 128;
        float p0 = 0.f, p1 = 0.f, p2 = 0.f, p3 = 0.f;
        #pragma unroll
        for (int i = 0; i < 8; ++i) {
            const int d4 = (q << 3) + i;
            const float4 wv4 = *(const float4*)(rw + ((d4 ^ swz) << 2));
            const float4 s0 = *(const float4*)(&sB[(0 << 7) + (d4 << 2)]);
            const float4 s1 = *(const float4*)(&sB[(1 << 7) + (d4 << 2)]);
            const float4 s2 = *(const float4*)(&sB[(2 << 7) + (d4 << 2)]);
            const float4 s3 = *(const float4*)(&sB[(3 << 7) + (d4 << 2)]);
            p0 = fmaf(s0.x, wv4.x, p0); p0 = fmaf(s0.y, wv4.y, p0);
            p0 = fmaf(s0.z, wv4.z, p0); p0 = fmaf(s0.w, wv4.w, p0);
            p1 = fmaf(s1.x, wv4.x, p1); p1 = fmaf(s1.y, wv4.y, p1);
            p1 = fmaf(s1.z, wv4.z, p1); p1 = fmaf(s1.w, wv4.w, p1);
            p2 = fmaf(s2.x, wv4.x, p2); p2 = fmaf(s2.y, wv4.y, p2);
            p2 = fmaf(s2.z, wv4.z, p2); p2 = fmaf(s2.w, wv4.w, p2);
            p3 = fmaf(s3.x, wv4.x, p3); p3 = fmaf(s3.y, wv4.y, p3);
            p3 = fmaf(s3.z, wv4.z, p3); p3 = fmaf(s3.w, wv4.w, p3);
        }
        float4 pv; pv.x = p0; pv.y = p1; pv.z = p2; pv.w = p3;
        *(float4*)&sP[m * 20 + (q << 2)] = pv;
    }
    __syncthreads();   // B5: sP visible; Wc2T staged

    // combine2 -> sS (t1 row q); stage-1 sS readers finished before B4
    {
        const int base = m * 20 + q;
        const float tv = sP[base] + sP[base + 4] + sP[base + 8] + sP[base + 12]
                         + bc1k;
        sS[(q << 7) + m] = silu_f(tv);
    }
    __syncthreads();   // B5b: t1 visible

    // ---- Stage 3 partials: out = t1@Wc2 + bc2
    {
        const float* rw = sLo + m * 128;
        float p0 = 0.f, p1 = 0.f, p2 = 0.f, p3 = 0.f;
        #pragma unroll
        for (int i = 0; i < 8; ++i) {
            const int d4 = (q << 3) + i;
            const float4 wv4 = *(const float4*)(rw + ((d4 ^ swz) << 2));
            const float4 s0 = *(const float4*)(&sS[(0 << 7) + (d4 << 2)]);
            const float4 s1 = *(const float4*)(&sS[(1 << 7) + (d4 << 2)]);
            const float4 s2 = *(const float4*)(&sS[(2 << 7) + (d4 << 2)]);
            const float4 s3 = *(const float4*)(&sS[(3 << 7) + (d4 << 2)]);
            p0 = fmaf(s0.x, wv4.x, p0); p0 = fmaf(s0.y, wv4.y, p0);
            p0 = fmaf(s0.z, wv4.z, p0); p0 = fmaf(s0.w, wv4.w, p0);
            p1 = fmaf(s1.x, wv4.x, p1); p1 = fmaf(s1.y, wv4.y, p1);
            p1 = fmaf(s1.z, wv4.z, p1); p1 = fmaf(s1.w, wv4.w, p1);
            p2 = fmaf(s2.x, wv4.x, p2); p2 = fmaf(s2.y, wv4.y, p2);
            p2 = fmaf(s2.z, wv4.z, p2); p2 = fmaf(s2.w, wv4.w, p2);
            p3 = fmaf(s3.x, wv4.x, p3); p3 = fmaf(s3.y, wv4.y, p3);
            p3 = fmaf(s3.z, wv4.z, p3); p3 = fmaf(s3.w, wv4.w, p3);
        }
        float4 pv; pv.x = p0; pv.y = p1; pv.z = p2; pv.w = p3;
        *(float4*)&sP[m * 20 + (q << 2)] = pv;
    }
    __syncthreads();   // B6: sP visible

    // combine3 -> global store (coalesced: (row0+q)*CC + m == row0*CC + t)
    {
        const int base = m * 20 + q;
        const float ov = sP[base] + sP[base + 4] + sP[base + 8] + sP[base + 12]
                         + bc2k;
        out[(size_t)row0 * CC + t] = ov;
    }
}

extern "C" void kernel_launch(void* const* d_in, const int* in_sizes, int n_in,
                              void* d_out, int out_size, void* d_ws, size_t ws_size,
                              hipStream_t stream) {
    const float* h   = (const float*)d_in[0];
    const float* adj = (const float*)d_in[1];
    const float* W1a = (const float*)d_in[2];
    const float* W1b = (const float*)d_in[3];
    const float* b1  = (const float*)d_in[4];
    const float* W2  = (const float*)d_in[5];
    const float* b2  = (const float*)d_in[6];
    const float* Wc1 = (const float*)d_in[7];
    const float* bc1 = (const float*)d_in[8];
    const float* Wc2 = (const float*)d_in[9];
    const float* bc2 = (const float*)d_in[10];
    float* out = (float*)d_out;
    float* ws  = (float*)d_ws;

    k_proj<<<NBLK, TPB, 0, stream>>>(h, W1a, W1b, b1, W2, Wc1, Wc2, ws);
    k_msgout<<<NBLK, TPB, 0, stream>>>(adj, b2, bc1, bc2, ws, out);
}